// Round 9
// baseline (1206.957 us; speedup 1.0000x reference)
//
#include <hip/hip_runtime.h>
#include <cstddef>

#define EPSV 0.001f

static inline int idiv(int a, int b){ return (a + b - 1) / b; }
static inline int imin(int a, int b){ return a < b ? a : b; }

// ---------------------------------------------------------------------------
// Weight repack: w (CO,CI,kz,ky,kx) -> wp[(tap*CI+ci)*CO + co]
// ---------------------------------------------------------------------------
struct WPtrs { const float* w[9]; };

__global__ __launch_bounds__(256)
void repack_w(WPtrs ws, float* __restrict__ wp) {
  constexpr int off[10] = {0,6912,13824,27648,55296,110592,221184,331776,442368,454656};
  constexpr int COs[9] = {16,16,32,32,64,64,64,64,64};
  constexpr int CIs[9] = {16,16,16,32,32,64,64,64,64};
  constexpr int NTs[9] = {27,27,27,27,27,27,27,27,3};
  int idx = blockIdx.x * blockDim.x + threadIdx.x;
  if (idx >= off[9]) return;
  int L = 0;
  #pragma unroll
  for (int k = 0; k < 9; k++) if (idx >= off[k+1]) L = k + 1;
  int r  = idx - off[L];
  int CO = COs[L], CI = CIs[L], NT = NTs[L];
  int co = r % CO; int t = r / CO; int ci = t % CI; int tap = t / CI;
  wp[idx] = ws.w[L][(co*CI + ci)*NT + tap];
}

// ---------------------------------------------------------------------------
// Tail-layer weight repack: w (64,64,taps) -> wq[(tap*64+co)*64+ci]
// ---------------------------------------------------------------------------
__global__ __launch_bounds__(256)
void repack_wq(const float* __restrict__ w6, const float* __restrict__ w7,
               const float* __restrict__ w8, float* __restrict__ wq) {
  constexpr int N6 = 110592, N7 = 110592, N8 = 12288;
  int idx = blockIdx.x * blockDim.x + threadIdx.x;
  if (idx >= N6 + N7 + N8) return;
  const float* src; int r; int NT;
  if (idx < N6)            { src = w6; r = idx;          NT = 27; }
  else if (idx < N6 + N7)  { src = w7; r = idx - N6;     NT = 27; }
  else                     { src = w8; r = idx - N6 - N7; NT = 3; }
  int ci = r % 64; int t = r / 64; int co = t % 64; int tap = t / 64;
  wq[idx] = src[(co*64 + ci)*NT + tap];
}

// ---------------------------------------------------------------------------
__global__ __launch_bounds__(256)
void scatter_grid(const int* __restrict__ coors, int* __restrict__ grid, int n) {
  int i = blockIdx.x * blockDim.x + threadIdx.x;
  if (i >= n) return;
  int z = coors[4*i+1], y = coors[4*i+2], x = coors[4*i+3];
  grid[(z*200 + y)*200 + x] = i;
}

// ---------------------------------------------------------------------------
// Sparse submanifold 3x3x3 conv, 16->16, over active voxel list.
// ---------------------------------------------------------------------------
__global__ __launch_bounds__(256)
void subm16(const float* __restrict__ fin, float* __restrict__ fout,
            const int* __restrict__ coors, const int* __restrict__ grid,
            const float* __restrict__ wp, int n) {
  int i = blockIdx.x * blockDim.x + threadIdx.x;
  if (i >= n) return;
  int z = coors[4*i+1], y = coors[4*i+2], x = coors[4*i+3];
  float acc[16];
  #pragma unroll
  for (int c = 0; c < 16; c++) acc[c] = 0.f;
  for (int kz = 0; kz < 3; kz++) {
    int iz = z + kz - 1; if ((unsigned)iz >= 40u) continue;
    for (int ky = 0; ky < 3; ky++) {
      int iy = y + ky - 1; if ((unsigned)iy >= 200u) continue;
      for (int kx = 0; kx < 3; kx++) {
        int ix = x + kx - 1; if ((unsigned)ix >= 200u) continue;
        int j = grid[(iz*200 + iy)*200 + ix];
        if (j < 0) continue;
        int tap = (kz*3 + ky)*3 + kx;
        const float* fj = fin + (size_t)j*16;
        const float* wb = wp + tap*16*16;
        #pragma unroll
        for (int cq = 0; cq < 4; cq++) {
          float4 av = *reinterpret_cast<const float4*>(fj + cq*4);
          float aj[4] = {av.x, av.y, av.z, av.w};
          #pragma unroll
          for (int j4 = 0; j4 < 4; j4++) {
            #pragma unroll
            for (int c = 0; c < 16; c++) acc[c] += aj[j4] * wb[(cq*4+j4)*16 + c];
          }
        }
      }
    }
  }
  float* o = fout + (size_t)i*16;
  #pragma unroll
  for (int c = 0; c < 16; c++) o[c] = acc[c];
}

// ---------------------------------------------------------------------------
// L2: strided (2,2,2) pad(1,1,1) 3x3x3 conv 16->32, sparse -> dense
// channels-last (20,100,100,32) + new mask. COPT=16, grid.y=2.
// ---------------------------------------------------------------------------
__global__ __launch_bounds__(256)
void down16to32(const float* __restrict__ fin, const int* __restrict__ grid,
                float* __restrict__ out, unsigned char* __restrict__ mout,
                const float* __restrict__ wp) {
  constexpr int OD = 20, OH = 100, OW = 100, COPT = 16;
  int vox = blockIdx.x * blockDim.x + threadIdx.x;
  int cog = blockIdx.y;
  if (vox >= OD*OH*OW) return;
  int ox = vox % OW; int t = vox / OW; int oy = t % OH; int oz = t / OH;
  float acc[COPT];
  #pragma unroll
  for (int c = 0; c < COPT; c++) acc[c] = 0.f;
  bool any = false;
  for (int kz = 0; kz < 3; kz++) {
    int iz = oz*2 - 1 + kz; if ((unsigned)iz >= 40u) continue;
    for (int ky = 0; ky < 3; ky++) {
      int iy = oy*2 - 1 + ky; if ((unsigned)iy >= 200u) continue;
      for (int kx = 0; kx < 3; kx++) {
        int ix = ox*2 - 1 + kx; if ((unsigned)ix >= 200u) continue;
        int j = grid[(iz*200 + iy)*200 + ix];
        if (j < 0) continue;
        any = true;
        int tap = (kz*3 + ky)*3 + kx;
        const float* fj = fin + (size_t)j*16;
        const float* wb = wp + (size_t)tap*16*32 + cog*COPT;
        #pragma unroll
        for (int cq = 0; cq < 4; cq++) {
          float4 av = *reinterpret_cast<const float4*>(fj + cq*4);
          float aj[4] = {av.x, av.y, av.z, av.w};
          #pragma unroll
          for (int j4 = 0; j4 < 4; j4++) {
            #pragma unroll
            for (int c = 0; c < COPT; c++) acc[c] += aj[j4] * wb[(cq*4+j4)*32 + c];
          }
        }
      }
    }
  }
  float* o = out + (size_t)vox*32 + cog*COPT;
  #pragma unroll
  for (int c = 0; c < COPT; c++) o[c] = acc[c];
  if (cog == 0) mout[vox] = any ? 1 : 0;
}

// ---------------------------------------------------------------------------
// LDS implicit-GEMM dense conv, channels-last (generic, per-tap staging).
// ---------------------------------------------------------------------------
template<int ID,int IH,int IW,int OD,int OH,int OW,int CI,int CO,
         int S,int VX,int CO2,
         int KD,int KH,int KW,int SD,int SH,int SW,int PD,int PH,int PW>
__global__ __launch_bounds__(256)
void convg(const float* __restrict__ in, float* __restrict__ out,
           const float* __restrict__ wp) {
  constexpr int G    = 256 / S;
  static_assert(G * CO2 == CO, "co tiling mismatch");
  constexpr int VT   = S * VX;
  constexpr int NVOX = OD*OH*OW;
  __shared__ float a_lds[VT * CI];
  __shared__ float w_lds[CI * CO];

  const int g   = threadIdx.x % G;
  const int s   = threadIdx.x / G;
  const int co0 = g * CO2;
  const int vbase = blockIdx.x * VT;

  float acc[VX][CO2];
  #pragma unroll
  for (int u = 0; u < VX; u++)
    #pragma unroll
    for (int cc = 0; cc < CO2; cc++) acc[u][cc] = 0.f;

  constexpr int CI4N = CI / 4;
  constexpr int VST  = 256 / CI4N;
  const int sv  = threadIdx.x / CI4N;
  const int sc4 = threadIdx.x % CI4N;

  #pragma unroll 1
  for (int kz = 0; kz < KD; kz++) {
    #pragma unroll 1
    for (int ky = 0; ky < KH; ky++) {
      #pragma unroll 1
      for (int kx = 0; kx < KW; kx++) {
        __syncthreads();
        const float* wt = wp + (size_t)((kz*KH + ky)*KW + kx) * CI * CO;
        #pragma unroll
        for (int i = 0; i < CI*CO/4/256; i++) {
          int idx = threadIdx.x + i*256;
          *reinterpret_cast<float4*>(&w_lds[idx*4]) =
              *reinterpret_cast<const float4*>(wt + idx*4);
        }
        #pragma unroll
        for (int rsub = 0; rsub < VT/VST; rsub++) {
          int vox = rsub*VST + sv;
          int gv  = vbase + vox;
          int vc  = gv < NVOX ? gv : 0;
          int ox = vc % OW; int tt = vc / OW; int oy = tt % OH; int oz = tt / OH;
          int iz = oz*SD - PD + kz;
          int iy = oy*SH - PH + ky;
          int ix = ox*SW - PW + kx;
          bool ok = (gv < NVOX) & ((unsigned)iz < (unsigned)ID)
                  & ((unsigned)iy < (unsigned)IH) & ((unsigned)ix < (unsigned)IW);
          float4 v = make_float4(0.f,0.f,0.f,0.f);
          if (ok) {
            int ipos = (iz*IH + iy)*IW + ix;
            v = *reinterpret_cast<const float4*>(in + (size_t)ipos*CI + sc4*4);
          }
          int dw = vox*CI + ((sc4*4) ^ ((vox & 7) << 2));
          *reinterpret_cast<float4*>(&a_lds[dw]) = v;
        }
        __syncthreads();
        #pragma unroll
        for (int c4 = 0; c4 < CI/4; c4++) {
          float wr[4][CO2];
          #pragma unroll
          for (int jj = 0; jj < 4; jj++)
            #pragma unroll
            for (int q = 0; q < CO2/4; q++) {
              float4 wv = *reinterpret_cast<const float4*>(
                  &w_lds[(c4*4 + jj)*CO + co0 + q*4]);
              wr[jj][q*4+0] = wv.x; wr[jj][q*4+1] = wv.y;
              wr[jj][q*4+2] = wv.z; wr[jj][q*4+3] = wv.w;
            }
          #pragma unroll
          for (int u = 0; u < VX; u++) {
            int r = s + S*u;
            float4 a4 = *reinterpret_cast<const float4*>(
                &a_lds[r*CI + ((c4*4) ^ ((r & 7) << 2))]);
            float av[4] = {a4.x, a4.y, a4.z, a4.w};
            #pragma unroll
            for (int jj = 0; jj < 4; jj++)
              #pragma unroll
              for (int cc = 0; cc < CO2; cc++)
                acc[u][cc] += av[jj] * wr[jj][cc];
          }
        }
      }
    }
  }
  #pragma unroll
  for (int u = 0; u < VX; u++) {
    int gv = vbase + s + S*u;
    if (gv >= NVOX) continue;
    float* o = out + (size_t)gv*CO + co0;
    #pragma unroll
    for (int q = 0; q < CO2/4; q++) {
      float4 v = make_float4(acc[u][q*4+0], acc[u][q*4+1],
                             acc[u][q*4+2], acc[u][q*4+3]);
      *reinterpret_cast<float4*>(o + q*4) = v;
    }
  }
}

// ---------------------------------------------------------------------------
// Halo LDS implicit-GEMM for SUBM 3x3x3 stride-1 pad-1 convs.
// Stages A once per (kz,ky) with a +-1-voxel halo (x-shift = linear-index
// shift); computes all 3 kx taps from shifted LDS slots. Row-wrap
// contributions killed by per-voxel x-edge masks (folded at compile time
// for kx==1). Staging passes/barrier pairs: 27 -> 9.
// ---------------------------------------------------------------------------
template<int D,int H,int W,int CI,int CO,int S,int VX,int CO2>
__global__ __launch_bounds__(256)
void convh(const float* __restrict__ in, float* __restrict__ out,
           const float* __restrict__ wp) {
  constexpr int G     = 256 / S;
  static_assert(G * CO2 == CO, "co tiling mismatch");
  constexpr int VT    = S * VX;
  constexpr int NVOX  = D*H*W;
  constexpr int NSLOT = VT + 2;
  __shared__ float a_lds[NSLOT * CI];
  __shared__ float w_lds[3 * CI * CO];

  const int g   = threadIdx.x % G;
  const int s   = threadIdx.x / G;
  const int co0 = g * CO2;
  const int vbase = blockIdx.x * VT;

  float acc[VX][CO2];
  #pragma unroll
  for (int u = 0; u < VX; u++)
    #pragma unroll
    for (int cc = 0; cc < CO2; cc++) acc[u][cc] = 0.f;

  // x-edge masks per owned voxel
  float m0[VX], m2[VX];
  #pragma unroll
  for (int u = 0; u < VX; u++) {
    int ox = (vbase + s + S*u) % W;
    m0[u] = ox > 0     ? 1.f : 0.f;
    m2[u] = ox < W - 1 ? 1.f : 0.f;
  }

  constexpr int CI4N = CI / 4;
  constexpr int VST  = 256 / CI4N;
  const int sv  = threadIdx.x / CI4N;
  const int sc4 = threadIdx.x % CI4N;

  #pragma unroll 1
  for (int kzy = 0; kzy < 9; kzy++) {
    int kz = kzy / 3, ky = kzy % 3;
    __syncthreads();
    // ---- stage W for the 3 kx taps of this (kz,ky) ----
    const float* wt = wp + (size_t)(kzy * 3) * CI * CO;
    #pragma unroll
    for (int i = 0; i < 3*CI*CO/4/256; i++) {
      int idx = threadIdx.x + i*256;
      *reinterpret_cast<float4*>(&w_lds[idx*4]) =
          *reinterpret_cast<const float4*>(wt + idx*4);
    }
    // ---- stage A slots [0, VT+2): voxel gv = vbase-1+t, shifted in z,y ----
    #pragma unroll
    for (int rsub = 0; rsub < (NSLOT*CI4N + 255)/256; rsub++) {
      int t = rsub*VST + sv;
      if (t < NSLOT) {
        int gv  = vbase - 1 + t;
        int gvc = min(max(gv, 0), NVOX-1);
        int ox = gvc % W; int tt = gvc / W; int oy = tt % H; int oz = tt / H;
        int iz = oz + kz - 1, iy = oy + ky - 1;
        bool ok = (gv >= 0) & (gv < NVOX) & ((unsigned)iz < (unsigned)D)
                & ((unsigned)iy < (unsigned)H);
        float4 v = make_float4(0.f,0.f,0.f,0.f);
        if (ok) {
          int ipos = (iz*H + iy)*W + ox;
          v = *reinterpret_cast<const float4*>(in + (size_t)ipos*CI + sc4*4);
        }
        *reinterpret_cast<float4*>(&a_lds[t*CI + ((sc4*4) ^ ((t & 7) << 2))]) = v;
      }
    }
    __syncthreads();
    // ---- compute 3 kx taps from shifted LDS slots ----
    #pragma unroll
    for (int kx = 0; kx < 3; kx++) {
      #pragma unroll 2
      for (int c4 = 0; c4 < CI/4; c4++) {
        float wr[4][CO2];
        #pragma unroll
        for (int jj = 0; jj < 4; jj++)
          #pragma unroll
          for (int q = 0; q < CO2/4; q++) {
            float4 wv = *reinterpret_cast<const float4*>(
                &w_lds[kx*CI*CO + (c4*4 + jj)*CO + co0 + q*4]);
            wr[jj][q*4+0] = wv.x; wr[jj][q*4+1] = wv.y;
            wr[jj][q*4+2] = wv.z; wr[jj][q*4+3] = wv.w;
          }
        #pragma unroll
        for (int u = 0; u < VX; u++) {
          int slot = s + S*u + kx;
          float4 a4 = *reinterpret_cast<const float4*>(
              &a_lds[slot*CI + ((c4*4) ^ ((slot & 7) << 2))]);
          float msk = (kx == 0) ? m0[u] : (kx == 2) ? m2[u] : 1.f;
          float av[4] = {a4.x*msk, a4.y*msk, a4.z*msk, a4.w*msk};
          #pragma unroll
          for (int jj = 0; jj < 4; jj++)
            #pragma unroll
            for (int cc = 0; cc < CO2; cc++)
              acc[u][cc] += av[jj] * wr[jj][cc];
        }
      }
    }
  }
  // ---- epilogue ----
  #pragma unroll
  for (int u = 0; u < VX; u++) {
    int gv = vbase + s + S*u;
    if (gv >= NVOX) continue;
    float* o = out + (size_t)gv*CO + co0;
    #pragma unroll
    for (int q = 0; q < CO2/4; q++) {
      float4 v = make_float4(acc[u][q*4+0], acc[u][q*4+1],
                             acc[u][q*4+2], acc[u][q*4+3]);
      *reinterpret_cast<float4*>(o + q*4) = v;
    }
  }
}

// ---------------------------------------------------------------------------
// Tail dense conv 64->64: ONE BLOCK PER OUTPUT VOXEL.
// ---------------------------------------------------------------------------
template<int ID,int IH,int IW,int OD,int OH,int OW,
         int KD,int KH,int KW,int SD,int SH,int SW,int PD,int PH,int PW>
__global__ __launch_bounds__(256)
void convt(const float* __restrict__ in, float* __restrict__ out,
           const float* __restrict__ wq) {
  constexpr int NT = KD*KH*KW;
  constexpr int NG = (NT + 3) / 4;
  const int v    = blockIdx.x;
  const int lane = threadIdx.x & 63;
  const int q    = threadIdx.x >> 6;
  int ox = v % OW; int t = v / OW; int oy = t % OH; int oz = t / OH;

  __shared__ float a_lds[4][64];
  __shared__ float red[4][64];
  float acc = 0.f;

  #pragma unroll 1
  for (int tg = 0; tg < NG; tg++) {
    int tap = tg*4 + q;
    float val = 0.f;
    if (tap < NT) {
      int kz = tap / (KH*KW); int rr = tap % (KH*KW);
      int ky = rr / KW;       int kx = rr % KW;
      int iz = oz*SD - PD + kz, iy = oy*SH - PH + ky, ix = ox*SW - PW + kx;
      if ((unsigned)iz < (unsigned)ID && (unsigned)iy < (unsigned)IH &&
          (unsigned)ix < (unsigned)IW)
        val = in[(size_t)((iz*IH + iy)*IW + ix)*64 + lane];
    }
    __syncthreads();
    a_lds[q][lane] = val;
    __syncthreads();
    #pragma unroll
    for (int t4 = 0; t4 < 4; t4++) {
      int tap2 = tg*4 + t4;
      if (tap2 >= NT) break;
      const float* wrow = wq + ((size_t)tap2*64 + lane)*64 + q*16;
      #pragma unroll
      for (int c4 = 0; c4 < 4; c4++) {
        float4 w4 = *reinterpret_cast<const float4*>(wrow + c4*4);
        acc += w4.x * a_lds[t4][q*16 + c4*4 + 0];
        acc += w4.y * a_lds[t4][q*16 + c4*4 + 1];
        acc += w4.z * a_lds[t4][q*16 + c4*4 + 2];
        acc += w4.w * a_lds[t4][q*16 + c4*4 + 3];
      }
    }
  }
  red[q][lane] = acc;
  __syncthreads();
  if (q == 0) {
    float s = red[0][lane] + red[1][lane] + red[2][lane] + red[3][lane];
    out[(size_t)v*64 + lane] = s;
  }
}

// ---------------------------------------------------------------------------
// Downsample mask: mout[v] = OR over taps of in-bounds min_.
// ---------------------------------------------------------------------------
template<int ID,int IH,int IW,int OD,int OH,int OW,int KD,int KH,int KW,
         int SD,int SH,int SW,int PD,int PH,int PW>
__global__ __launch_bounds__(256)
void mask_down(const unsigned char* __restrict__ min_, unsigned char* __restrict__ mout) {
  int v = blockIdx.x * blockDim.x + threadIdx.x;
  if (v >= OD*OH*OW) return;
  int ox = v % OW; int t = v / OW; int oy = t % OH; int oz = t / OH;
  bool any = false;
  for (int kz = 0; kz < KD; kz++) {
    int iz = oz*SD - PD + kz; if ((unsigned)iz >= (unsigned)ID) continue;
    for (int ky = 0; ky < KH; ky++) {
      int iy = oy*SH - PH + ky; if ((unsigned)iy >= (unsigned)IH) continue;
      for (int kx = 0; kx < KW; kx++) {
        int ix = ox*SW - PW + kx; if ((unsigned)ix >= (unsigned)IW) continue;
        any = any || (min_[(iz*IH + iy)*IW + ix] != 0);
      }
    }
  }
  mout[v] = any ? 1 : 0;
}

// ---------------------------------------------------------------------------
// Masked BN stats: per-channel sum, sumsq, count.
// ---------------------------------------------------------------------------
template<int CO, int YD>
__global__ void bn_stats(const float* __restrict__ x, const unsigned char* __restrict__ m,
                         float* __restrict__ stats, int nvox) {
  int c  = threadIdx.x;
  int ty = threadIdx.y;
  float s = 0.f, q = 0.f, cnt = 0.f;
  for (int vox = blockIdx.x*YD + ty; vox < nvox; vox += gridDim.x*YD) {
    bool act = m ? (m[vox] != 0) : true;
    if (act) {
      float v = x[(size_t)vox*CO + c];
      s += v; q += v*v; cnt += 1.f;
    }
  }
  __shared__ float ls[YD][CO];
  __shared__ float lq[YD][CO];
  __shared__ float lc[YD];
  ls[ty][c] = s; lq[ty][c] = q;
  if (c == 0) lc[ty] = cnt;
  __syncthreads();
  if (ty == 0) {
    #pragma unroll
    for (int i = 1; i < YD; i++) { s += ls[i][c]; q += lq[i][c]; }
    atomicAdd(&stats[c], s);
    atomicAdd(&stats[CO + c], q);
    if (c == 0) {
      float tc = 0.f;
      #pragma unroll
      for (int i = 0; i < YD; i++) tc += lc[i];
      atomicAdd(&stats[2*CO], tc);
    }
  }
}

// ---------------------------------------------------------------------------
template<int CO>
__global__ __launch_bounds__(256)
void bn_apply(float* __restrict__ x, const unsigned char* __restrict__ m,
              const float* __restrict__ stats, const float* __restrict__ g,
              const float* __restrict__ b, int nvox) {
  int idx = blockIdx.x * blockDim.x + threadIdx.x;
  int vox = idx / CO, c = idx % CO;
  if (vox >= nvox) return;
  float cnt   = fmaxf(stats[2*CO], 1.f);
  float mean  = stats[c] / cnt;
  float var   = stats[CO + c] / cnt - mean*mean;
  float scale = g[c] * rsqrtf(var + EPSV);
  float v = (x[idx] - mean) * scale + b[c];
  v = fmaxf(v, 0.f);
  bool act = m ? (m[vox] != 0) : true;
  x[idx] = act ? v : 0.f;
}

// ---------------------------------------------------------------------------
__global__ __launch_bounds__(256)
void write_out(const float* __restrict__ x, float* __restrict__ out) {
  int idx = blockIdx.x * blockDim.x + threadIdx.x;
  if (idx >= 64*11*5*25) return;
  int y = idx % 25; int t = idx / 25;
  int z = t % 5;  t /= 5;
  int wx = t % 11; int c = t / 11;
  out[idx] = x[(((z*25 + y)*11) + wx)*64 + c];
}

// ---------------------------------------------------------------------------
extern "C" void kernel_launch(void* const* d_in, const int* in_sizes, int n_in,
                              void* d_out, int out_size, void* d_ws, size_t ws_size,
                              hipStream_t stream) {
  const float* vf    = (const float*)d_in[0];
  const int*   coors = (const int*)d_in[1];
  int n = in_sizes[0] / 16;

  // dict order is INTERLEAVED: vf, coors, bs, shape, (w0,g0,b0), (w1,g1,b1), ...
  const float *w[9], *g[9], *b[9];
  for (int i = 0; i < 9; i++) {
    w[i] = (const float*)d_in[4 + 3*i];
    g[i] = (const float*)d_in[5 + 3*i];
    b[i] = (const float*)d_in[6 + 3*i];
  }
  float* out = (float*)d_out;

  char* wsb = (char*)d_ws;
  size_t off = 0;
  auto alloc = [&](size_t bytes) -> void* {
    void* p = wsb + off;
    off += (bytes + 255) & ~(size_t)255;
    return p;
  };
  int*   grid0 = (int*)  alloc((size_t)40*200*200*4);
  float* wp    = (float*)alloc((size_t)454656*4);
  float* wq    = (float*)alloc((size_t)233472*4);
  float* fA    = (float*)alloc((size_t)n*16*4);
  float* fB    = (float*)alloc((size_t)n*16*4);
  float* dA    = (float*)alloc((size_t)20*100*100*32*4);
  float* dB    = (float*)alloc((size_t)20*100*100*32*4);
  unsigned char* m2 = (unsigned char*)alloc(20*100*100);
  unsigned char* m4 = (unsigned char*)alloc(10*50*50);
  unsigned char* m6 = (unsigned char*)alloc(5*25*24);
  unsigned char* m8 = (unsigned char*)alloc(5*25*11);
  float* stats = (float*)alloc((size_t)9*160*4);

  float* st[9];
  for (int i = 0; i < 9; i++) st[i] = stats + i*160;

  hipMemsetAsync(grid0, 0xFF, (size_t)40*200*200*4, stream);
  hipMemsetAsync(stats, 0, (size_t)9*160*4, stream);

  WPtrs wps; for (int i = 0; i < 9; i++) wps.w[i] = w[i];
  repack_w<<<idiv(454656,256), 256, 0, stream>>>(wps, wp);
  repack_wq<<<idiv(233472,256), 256, 0, stream>>>(w[6], w[7], w[8], wq);
  scatter_grid<<<idiv(n,256), 256, 0, stream>>>(coors, grid0, n);

  const int WO0=0, WO1=6912, WO2=13824, WO3=27648, WO4=55296,
            WO5=110592;
  const int WQ6=0, WQ7=110592, WQ8=221184;

  // ---- L0, L1: sparse subm 16->16 ----
  subm16<<<idiv(n,256), 256, 0, stream>>>(vf, fA, coors, grid0, wp + WO0, n);
  bn_stats<16,16><<<imin(256, idiv(n,16)), dim3(16,16), 0, stream>>>(fA, nullptr, st[0], n);
  bn_apply<16><<<idiv(n*16,256), 256, 0, stream>>>(fA, nullptr, st[0], g[0], b[0], n);

  subm16<<<idiv(n,256), 256, 0, stream>>>(fA, fB, coors, grid0, wp + WO1, n);
  bn_stats<16,16><<<imin(256, idiv(n,16)), dim3(16,16), 0, stream>>>(fB, nullptr, st[1], n);
  bn_apply<16><<<idiv(n*16,256), 256, 0, stream>>>(fB, nullptr, st[1], g[1], b[1], n);

  // ---- L2: down 16->32 -> dense (20,100,100), COPT=16 x 2 groups ----
  down16to32<<<dim3(idiv(200000,256),2), 256, 0, stream>>>(fB, grid0, dA, m2, wp + WO2);
  bn_stats<32,8><<<imin(256, idiv(200000,8)), dim3(32,8), 0, stream>>>(dA, m2, st[2], 200000);
  bn_apply<32><<<idiv(200000*32,256), 256, 0, stream>>>(dA, m2, st[2], g[2], b[2], 200000);

  // ---- L3: subm 32->32 dense, HALO LDS-GEMM (stage per (kz,ky)) ----
  convh<20,100,100, 32,32, 32,8,4>
      <<<idiv(200000,256), 256, 0, stream>>>(dA, dB, wp + WO3);
  bn_stats<32,8><<<imin(256, idiv(200000,8)), dim3(32,8), 0, stream>>>(dB, m2, st[3], 200000);
  bn_apply<32><<<idiv(200000*32,256), 256, 0, stream>>>(dB, m2, st[3], g[3], b[3], 200000);

  // ---- L4: down 32->64 -> (10,50,50), VT=64 (S=16,VX=4,CO2=4) + mask ----
  convg<20,100,100, 10,50,50, 32,64, 16,4,4, 3,3,3, 2,2,2, 1,1,1>
      <<<idiv(25000,64), 256, 0, stream>>>(dB, dA, wp + WO4);
  mask_down<20,100,100, 10,50,50, 3,3,3, 2,2,2, 1,1,1>
      <<<idiv(25000,256), 256, 0, stream>>>(m2, m4);
  bn_stats<64,4><<<imin(256, idiv(25000,4)), dim3(64,4), 0, stream>>>(dA, m4, st[4], 25000);
  bn_apply<64><<<idiv(25000*64,256), 256, 0, stream>>>(dA, m4, st[4], g[4], b[4], 25000);

  // ---- L5: subm 64->64, VT=64 (S=16,VX=4,CO2=4) ----
  convg<10,50,50, 10,50,50, 64,64, 16,4,4, 3,3,3, 1,1,1, 1,1,1>
      <<<idiv(25000,64), 256, 0, stream>>>(dA, dB, wp + WO5);
  bn_stats<64,4><<<imin(256, idiv(25000,4)), dim3(64,4), 0, stream>>>(dB, m4, st[5], 25000);
  bn_apply<64><<<idiv(25000*64,256), 256, 0, stream>>>(dB, m4, st[5], g[5], b[5], 25000);

  // ---- L6: down 64->64 s(2,2,2) p(1,1,0) -> (5,25,24), block-per-voxel ----
  convt<10,50,50, 5,25,24, 3,3,3, 2,2,2, 1,1,0>
      <<<3000, 256, 0, stream>>>(dB, dA, wq + WQ6);
  mask_down<10,50,50, 5,25,24, 3,3,3, 2,2,2, 1,1,0>
      <<<idiv(3000,256), 256, 0, stream>>>(m4, m6);
  bn_stats<64,4><<<imin(256, idiv(3000,4)), dim3(64,4), 0, stream>>>(dA, m6, st[6], 3000);
  bn_apply<64><<<idiv(3000*64,256), 256, 0, stream>>>(dA, m6, st[6], g[6], b[6], 3000);

  // ---- L7: subm 64->64, block-per-voxel ----
  convt<5,25,24, 5,25,24, 3,3,3, 1,1,1, 1,1,1>
      <<<3000, 256, 0, stream>>>(dA, dB, wq + WQ7);
  bn_stats<64,4><<<imin(256, idiv(3000,4)), dim3(64,4), 0, stream>>>(dB, m6, st[7], 3000);
  bn_apply<64><<<idiv(3000*64,256), 256, 0, stream>>>(dB, m6, st[7], g[7], b[7], 3000);

  // ---- L8: down 64->64 k(1,1,3) s(1,1,2) -> (5,25,11), block-per-voxel ----
  convt<5,25,24, 5,25,11, 1,1,3, 1,1,2, 0,0,0>
      <<<1375, 256, 0, stream>>>(dB, dA, wq + WQ8);
  mask_down<5,25,24, 5,25,11, 1,1,3, 1,1,2, 0,0,0>
      <<<idiv(1375,256), 256, 0, stream>>>(m6, m8);
  bn_stats<64,4><<<imin(256, idiv(1375,4)), dim3(64,4), 0, stream>>>(dA, m8, st[8], 1375);
  bn_apply<64><<<idiv(1375*64,256), 256, 0, stream>>>(dA, m8, st[8], g[8], b[8], 1375);

  write_out<<<idiv(88000,256), 256, 0, stream>>>(dA, out);
}

// Round 11
// 1021.075 us; speedup vs baseline: 1.1820x; 1.1820x over previous
//
#include <hip/hip_runtime.h>
#include <cstddef>

#define EPSV 0.001f

static inline int idiv(int a, int b){ return (a + b - 1) / b; }
static inline int imin(int a, int b){ return a < b ? a : b; }

typedef __attribute__((ext_vector_type(8))) short short8b;
typedef __attribute__((ext_vector_type(4))) float floatx4;

// float -> bf16 round-to-nearest-even
static __device__ inline unsigned short f2bf(float f) {
  unsigned u = __float_as_uint(f);
  unsigned r = (u + 0x7FFFu + ((u >> 16) & 1u)) >> 16;
  return (unsigned short)r;
}

// ---------------------------------------------------------------------------
// Weight repack: w (CO,CI,kz,ky,kx) -> wp[(tap*CI+ci)*CO + co]
// ---------------------------------------------------------------------------
struct WPtrs { const float* w[9]; };

__global__ __launch_bounds__(256)
void repack_w(WPtrs ws, float* __restrict__ wp) {
  constexpr int off[10] = {0,6912,13824,27648,55296,110592,221184,331776,442368,454656};
  constexpr int COs[9] = {16,16,32,32,64,64,64,64,64};
  constexpr int CIs[9] = {16,16,16,32,32,64,64,64,64};
  constexpr int NTs[9] = {27,27,27,27,27,27,27,27,3};
  int idx = blockIdx.x * blockDim.x + threadIdx.x;
  if (idx >= off[9]) return;
  int L = 0;
  #pragma unroll
  for (int k = 0; k < 9; k++) if (idx >= off[k+1]) L = k + 1;
  int r  = idx - off[L];
  int CO = COs[L], CI = CIs[L], NT = NTs[L];
  int co = r % CO; int t = r / CO; int ci = t % CI; int tap = t / CI;
  wp[idx] = ws.w[L][(co*CI + ci)*NT + tap];
}

// ---------------------------------------------------------------------------
// Tail-layer weight repack: w (64,64,taps) -> wq[(tap*64+co)*64+ci]
// ---------------------------------------------------------------------------
__global__ __launch_bounds__(256)
void repack_wq(const float* __restrict__ w6, const float* __restrict__ w7,
               const float* __restrict__ w8, float* __restrict__ wq) {
  constexpr int N6 = 110592, N7 = 110592, N8 = 12288;
  int idx = blockIdx.x * blockDim.x + threadIdx.x;
  if (idx >= N6 + N7 + N8) return;
  const float* src; int r; int NT;
  if (idx < N6)            { src = w6; r = idx;          NT = 27; }
  else if (idx < N6 + N7)  { src = w7; r = idx - N6;     NT = 27; }
  else                     { src = w8; r = idx - N6 - N7; NT = 3; }
  int ci = r % 64; int t = r / 64; int co = t % 64; int tap = t / 64;
  wq[idx] = src[(co*64 + ci)*NT + tap];
}

// ---------------------------------------------------------------------------
// L3 bf16 weight repack: w3 (32,32,3,3,3) -> wq3[(tap*32+co)*32+ci] (bf16)
// ---------------------------------------------------------------------------
__global__ __launch_bounds__(256)
void repack_w3b(const float* __restrict__ w3, unsigned short* __restrict__ wq3) {
  int idx = blockIdx.x * blockDim.x + threadIdx.x;
  if (idx >= 27648) return;
  int ci = idx % 32; int t = idx / 32; int co = t % 32; int tap = t / 32;
  wq3[idx] = f2bf(w3[(co*32 + ci)*27 + tap]);
}

// ---------------------------------------------------------------------------
__global__ __launch_bounds__(256)
void scatter_grid(const int* __restrict__ coors, int* __restrict__ grid, int n) {
  int i = blockIdx.x * blockDim.x + threadIdx.x;
  if (i >= n) return;
  int z = coors[4*i+1], y = coors[4*i+2], x = coors[4*i+3];
  grid[(z*200 + y)*200 + x] = i;
}

// ---------------------------------------------------------------------------
// Sparse submanifold 3x3x3 conv, 16->16, over active voxel list.
// ---------------------------------------------------------------------------
__global__ __launch_bounds__(256)
void subm16(const float* __restrict__ fin, float* __restrict__ fout,
            const int* __restrict__ coors, const int* __restrict__ grid,
            const float* __restrict__ wp, int n) {
  int i = blockIdx.x * blockDim.x + threadIdx.x;
  if (i >= n) return;
  int z = coors[4*i+1], y = coors[4*i+2], x = coors[4*i+3];
  float acc[16];
  #pragma unroll
  for (int c = 0; c < 16; c++) acc[c] = 0.f;
  for (int kz = 0; kz < 3; kz++) {
    int iz = z + kz - 1; if ((unsigned)iz >= 40u) continue;
    for (int ky = 0; ky < 3; ky++) {
      int iy = y + ky - 1; if ((unsigned)iy >= 200u) continue;
      for (int kx = 0; kx < 3; kx++) {
        int ix = x + kx - 1; if ((unsigned)ix >= 200u) continue;
        int j = grid[(iz*200 + iy)*200 + ix];
        if (j < 0) continue;
        int tap = (kz*3 + ky)*3 + kx;
        const float* fj = fin + (size_t)j*16;
        const float* wb = wp + tap*16*16;
        #pragma unroll
        for (int cq = 0; cq < 4; cq++) {
          float4 av = *reinterpret_cast<const float4*>(fj + cq*4);
          float aj[4] = {av.x, av.y, av.z, av.w};
          #pragma unroll
          for (int j4 = 0; j4 < 4; j4++) {
            #pragma unroll
            for (int c = 0; c < 16; c++) acc[c] += aj[j4] * wb[(cq*4+j4)*16 + c];
          }
        }
      }
    }
  }
  float* o = fout + (size_t)i*16;
  #pragma unroll
  for (int c = 0; c < 16; c++) o[c] = acc[c];
}

// ---------------------------------------------------------------------------
// L2: strided (2,2,2) pad(1,1,1) 3x3x3 conv 16->32, sparse -> dense
// channels-last (20,100,100,32) + new mask. COPT=16, grid.y=2.
// ---------------------------------------------------------------------------
__global__ __launch_bounds__(256)
void down16to32(const float* __restrict__ fin, const int* __restrict__ grid,
                float* __restrict__ out, unsigned char* __restrict__ mout,
                const float* __restrict__ wp) {
  constexpr int OD = 20, OH = 100, OW = 100, COPT = 16;
  int vox = blockIdx.x * blockDim.x + threadIdx.x;
  int cog = blockIdx.y;
  if (vox >= OD*OH*OW) return;
  int ox = vox % OW; int t = vox / OW; int oy = t % OH; int oz = t / OH;
  float acc[COPT];
  #pragma unroll
  for (int c = 0; c < COPT; c++) acc[c] = 0.f;
  bool any = false;
  for (int kz = 0; kz < 3; kz++) {
    int iz = oz*2 - 1 + kz; if ((unsigned)iz >= 40u) continue;
    for (int ky = 0; ky < 3; ky++) {
      int iy = oy*2 - 1 + ky; if ((unsigned)iy >= 200u) continue;
      for (int kx = 0; kx < 3; kx++) {
        int ix = ox*2 - 1 + kx; if ((unsigned)ix >= 200u) continue;
        int j = grid[(iz*200 + iy)*200 + ix];
        if (j < 0) continue;
        any = true;
        int tap = (kz*3 + ky)*3 + kx;
        const float* fj = fin + (size_t)j*16;
        const float* wb = wp + (size_t)tap*16*32 + cog*COPT;
        #pragma unroll
        for (int cq = 0; cq < 4; cq++) {
          float4 av = *reinterpret_cast<const float4*>(fj + cq*4);
          float aj[4] = {av.x, av.y, av.z, av.w};
          #pragma unroll
          for (int j4 = 0; j4 < 4; j4++) {
            #pragma unroll
            for (int c = 0; c < COPT; c++) acc[c] += aj[j4] * wb[(cq*4+j4)*32 + c];
          }
        }
      }
    }
  }
  float* o = out + (size_t)vox*32 + cog*COPT;
  #pragma unroll
  for (int c = 0; c < COPT; c++) o[c] = acc[c];
  if (cog == 0) mout[vox] = any ? 1 : 0;
}

// ---------------------------------------------------------------------------
// L3 bf16 MFMA implicit-GEMM subm conv 32->32 on (20,100,100).
// Block = 64 voxels x 32 co, 4 waves; wave w: voxels [w*16,w*16+16) x 32 co.
// Per tap: stage A (64 vox x 32 ci bf16) + W ([co][ci] bf16) into LDS,
// one mfma_f32_16x16x32_bf16 per n-tile (K=32 per tap, 27 taps -> K=864).
// A-frag: lane l reads a_lds[row=l&15][k=(l>>4)*8..+8]; B-frag from
// w_lds[co=l&15][same k]; D: col=lane&15, row=(lane>>4)*4+reg  [m89 layout].
// LDS stride 40 ushorts (80B): 16B-aligned b128 reads, 2-way banks (free).
// ---------------------------------------------------------------------------
__global__ __launch_bounds__(256)
void convm3(const unsigned short* __restrict__ xb, float* __restrict__ out,
            const unsigned short* __restrict__ wq3) {
  constexpr int D = 20, H = 100, W = 100;
  constexpr int LDA = 40;
  __shared__ unsigned short a_lds[64 * LDA];
  __shared__ unsigned short w_lds[32 * LDA];

  const int tid  = threadIdx.x;
  const int lane = tid & 63;
  const int wv   = tid >> 6;
  const int vbase = blockIdx.x * 64;

  // staging role: thread = (svox, sq) covering 64 vox x 4 chunks of 8 bf16
  const int svox = tid >> 2, sq = tid & 3;
  int gv = vbase + svox;
  int sx = gv % W; int tt = gv / W; int sy = tt % H; int sz = tt / H;

  floatx4 acc0 = {0.f,0.f,0.f,0.f};
  floatx4 acc1 = {0.f,0.f,0.f,0.f};
  const int arow = wv*16 + (lane & 15);
  const int kc   = (lane >> 4) * 8;

  #pragma unroll 1
  for (int tap = 0; tap < 27; tap++) {
    int kz = tap / 9, r9 = tap % 9;
    int ky = r9 / 3, kx = r9 % 3;
    int iz = sz + kz - 1, iy = sy + ky - 1, ix = sx + kx - 1;
    bool ok = ((unsigned)iz < (unsigned)D) & ((unsigned)iy < (unsigned)H)
            & ((unsigned)ix < (unsigned)W);
    float4 av = make_float4(0.f,0.f,0.f,0.f);
    if (ok)
      av = *reinterpret_cast<const float4*>(
          xb + ((size_t)((iz*H + iy)*W + ix)*32 + sq*8));
    __syncthreads();  // previous iteration's MFMA reads done
    *reinterpret_cast<float4*>(&a_lds[svox*LDA + sq*8]) = av;
    if (tid < 128) {
      int co = tid >> 2, h = tid & 3;
      *reinterpret_cast<float4*>(&w_lds[co*LDA + h*8]) =
          *reinterpret_cast<const float4*>(wq3 + ((size_t)(tap*32 + co)*32 + h*8));
    }
    __syncthreads();
    short8b a  = *reinterpret_cast<const short8b*>(&a_lds[arow*LDA + kc]);
    short8b b0 = *reinterpret_cast<const short8b*>(&w_lds[(lane & 15)*LDA + kc]);
    short8b b1 = *reinterpret_cast<const short8b*>(&w_lds[(16 + (lane & 15))*LDA + kc]);
    acc0 = __builtin_amdgcn_mfma_f32_16x16x32_bf16(a, b0, acc0, 0, 0, 0);
    acc1 = __builtin_amdgcn_mfma_f32_16x16x32_bf16(a, b1, acc1, 0, 0, 0);
  }
  int orow = vbase + wv*16 + (lane >> 4) * 4;
  int ocol = lane & 15;
  #pragma unroll
  for (int rr = 0; rr < 4; rr++) {
    out[(size_t)(orow + rr)*32 + ocol]      = acc0[rr];
    out[(size_t)(orow + rr)*32 + 16 + ocol] = acc1[rr];
  }
}

// ---------------------------------------------------------------------------
// LDS implicit-GEMM dense conv, channels-last (generic, per-tap staging).
// ---------------------------------------------------------------------------
template<int ID,int IH,int IW,int OD,int OH,int OW,int CI,int CO,
         int S,int VX,int CO2,
         int KD,int KH,int KW,int SD,int SH,int SW,int PD,int PH,int PW>
__global__ __launch_bounds__(256)
void convg(const float* __restrict__ in, float* __restrict__ out,
           const float* __restrict__ wp) {
  constexpr int G    = 256 / S;
  static_assert(G * CO2 == CO, "co tiling mismatch");
  constexpr int VT   = S * VX;
  constexpr int NVOX = OD*OH*OW;
  __shared__ float a_lds[VT * CI];
  __shared__ float w_lds[CI * CO];

  const int g   = threadIdx.x % G;
  const int s   = threadIdx.x / G;
  const int co0 = g * CO2;
  const int vbase = blockIdx.x * VT;

  float acc[VX][CO2];
  #pragma unroll
  for (int u = 0; u < VX; u++)
    #pragma unroll
    for (int cc = 0; cc < CO2; cc++) acc[u][cc] = 0.f;

  constexpr int CI4N = CI / 4;
  constexpr int VST  = 256 / CI4N;
  const int sv  = threadIdx.x / CI4N;
  const int sc4 = threadIdx.x % CI4N;

  #pragma unroll 1
  for (int kz = 0; kz < KD; kz++) {
    #pragma unroll 1
    for (int ky = 0; ky < KH; ky++) {
      #pragma unroll 1
      for (int kx = 0; kx < KW; kx++) {
        __syncthreads();
        const float* wt = wp + (size_t)((kz*KH + ky)*KW + kx) * CI * CO;
        #pragma unroll
        for (int i = 0; i < CI*CO/4/256; i++) {
          int idx = threadIdx.x + i*256;
          *reinterpret_cast<float4*>(&w_lds[idx*4]) =
              *reinterpret_cast<const float4*>(wt + idx*4);
        }
        #pragma unroll
        for (int rsub = 0; rsub < VT/VST; rsub++) {
          int vox = rsub*VST + sv;
          int gv  = vbase + vox;
          int vc  = gv < NVOX ? gv : 0;
          int ox = vc % OW; int tt = vc / OW; int oy = tt % OH; int oz = tt / OH;
          int iz = oz*SD - PD + kz;
          int iy = oy*SH - PH + ky;
          int ix = ox*SW - PW + kx;
          bool ok = (gv < NVOX) & ((unsigned)iz < (unsigned)ID)
                  & ((unsigned)iy < (unsigned)IH) & ((unsigned)ix < (unsigned)IW);
          float4 v = make_float4(0.f,0.f,0.f,0.f);
          if (ok) {
            int ipos = (iz*IH + iy)*IW + ix;
            v = *reinterpret_cast<const float4*>(in + (size_t)ipos*CI + sc4*4);
          }
          int dw = vox*CI + ((sc4*4) ^ ((vox & 7) << 2));
          *reinterpret_cast<float4*>(&a_lds[dw]) = v;
        }
        __syncthreads();
        #pragma unroll
        for (int c4 = 0; c4 < CI/4; c4++) {
          float wr[4][CO2];
          #pragma unroll
          for (int jj = 0; jj < 4; jj++)
            #pragma unroll
            for (int q = 0; q < CO2/4; q++) {
              float4 wv = *reinterpret_cast<const float4*>(
                  &w_lds[(c4*4 + jj)*CO + co0 + q*4]);
              wr[jj][q*4+0] = wv.x; wr[jj][q*4+1] = wv.y;
              wr[jj][q*4+2] = wv.z; wr[jj][q*4+3] = wv.w;
            }
          #pragma unroll
          for (int u = 0; u < VX; u++) {
            int r = s + S*u;
            float4 a4 = *reinterpret_cast<const float4*>(
                &a_lds[r*CI + ((c4*4) ^ ((r & 7) << 2))]);
            float av[4] = {a4.x, a4.y, a4.z, a4.w};
            #pragma unroll
            for (int jj = 0; jj < 4; jj++)
              #pragma unroll
              for (int cc = 0; cc < CO2; cc++)
                acc[u][cc] += av[jj] * wr[jj][cc];
          }
        }
      }
    }
  }
  #pragma unroll
  for (int u = 0; u < VX; u++) {
    int gv = vbase + s + S*u;
    if (gv >= NVOX) continue;
    float* o = out + (size_t)gv*CO + co0;
    #pragma unroll
    for (int q = 0; q < CO2/4; q++) {
      float4 v = make_float4(acc[u][q*4+0], acc[u][q*4+1],
                             acc[u][q*4+2], acc[u][q*4+3]);
      *reinterpret_cast<float4*>(o + q*4) = v;
    }
  }
}

// ---------------------------------------------------------------------------
// Tail dense conv 64->64: ONE BLOCK PER OUTPUT VOXEL.
// ---------------------------------------------------------------------------
template<int ID,int IH,int IW,int OD,int OH,int OW,
         int KD,int KH,int KW,int SD,int SH,int SW,int PD,int PH,int PW>
__global__ __launch_bounds__(256)
void convt(const float* __restrict__ in, float* __restrict__ out,
           const float* __restrict__ wq) {
  constexpr int NT = KD*KH*KW;
  constexpr int NG = (NT + 3) / 4;
  const int v    = blockIdx.x;
  const int lane = threadIdx.x & 63;
  const int q    = threadIdx.x >> 6;
  int ox = v % OW; int t = v / OW; int oy = t % OH; int oz = t / OH;

  __shared__ float a_lds[4][64];
  __shared__ float red[4][64];
  float acc = 0.f;

  #pragma unroll 1
  for (int tg = 0; tg < NG; tg++) {
    int tap = tg*4 + q;
    float val = 0.f;
    if (tap < NT) {
      int kz = tap / (KH*KW); int rr = tap % (KH*KW);
      int ky = rr / KW;       int kx = rr % KW;
      int iz = oz*SD - PD + kz, iy = oy*SH - PH + ky, ix = ox*SW - PW + kx;
      if ((unsigned)iz < (unsigned)ID && (unsigned)iy < (unsigned)IH &&
          (unsigned)ix < (unsigned)IW)
        val = in[(size_t)((iz*IH + iy)*IW + ix)*64 + lane];
    }
    __syncthreads();
    a_lds[q][lane] = val;
    __syncthreads();
    #pragma unroll
    for (int t4 = 0; t4 < 4; t4++) {
      int tap2 = tg*4 + t4;
      if (tap2 >= NT) break;
      const float* wrow = wq + ((size_t)tap2*64 + lane)*64 + q*16;
      #pragma unroll
      for (int c4 = 0; c4 < 4; c4++) {
        float4 w4 = *reinterpret_cast<const float4*>(wrow + c4*4);
        acc += w4.x * a_lds[t4][q*16 + c4*4 + 0];
        acc += w4.y * a_lds[t4][q*16 + c4*4 + 1];
        acc += w4.z * a_lds[t4][q*16 + c4*4 + 2];
        acc += w4.w * a_lds[t4][q*16 + c4*4 + 3];
      }
    }
  }
  red[q][lane] = acc;
  __syncthreads();
  if (q == 0) {
    float s = red[0][lane] + red[1][lane] + red[2][lane] + red[3][lane];
    out[(size_t)v*64 + lane] = s;
  }
}

// ---------------------------------------------------------------------------
// Downsample mask: mout[v] = OR over taps of in-bounds min_.
// ---------------------------------------------------------------------------
template<int ID,int IH,int IW,int OD,int OH,int OW,int KD,int KH,int KW,
         int SD,int SH,int SW,int PD,int PH,int PW>
__global__ __launch_bounds__(256)
void mask_down(const unsigned char* __restrict__ min_, unsigned char* __restrict__ mout) {
  int v = blockIdx.x * blockDim.x + threadIdx.x;
  if (v >= OD*OH*OW) return;
  int ox = v % OW; int t = v / OW; int oy = t % OH; int oz = t / OH;
  bool any = false;
  for (int kz = 0; kz < KD; kz++) {
    int iz = oz*SD - PD + kz; if ((unsigned)iz >= (unsigned)ID) continue;
    for (int ky = 0; ky < KH; ky++) {
      int iy = oy*SH - PH + ky; if ((unsigned)iy >= (unsigned)IH) continue;
      for (int kx = 0; kx < KW; kx++) {
        int ix = ox*SW - PW + kx; if ((unsigned)ix >= (unsigned)IW) continue;
        any = any || (min_[(iz*IH + iy)*IW + ix] != 0);
      }
    }
  }
  mout[v] = any ? 1 : 0;
}

// ---------------------------------------------------------------------------
// Masked BN stats: per-channel sum, sumsq, count.
// ---------------------------------------------------------------------------
template<int CO, int YD>
__global__ void bn_stats(const float* __restrict__ x, const unsigned char* __restrict__ m,
                         float* __restrict__ stats, int nvox) {
  int c  = threadIdx.x;
  int ty = threadIdx.y;
  float s = 0.f, q = 0.f, cnt = 0.f;
  for (int vox = blockIdx.x*YD + ty; vox < nvox; vox += gridDim.x*YD) {
    bool act = m ? (m[vox] != 0) : true;
    if (act) {
      float v = x[(size_t)vox*CO + c];
      s += v; q += v*v; cnt += 1.f;
    }
  }
  __shared__ float ls[YD][CO];
  __shared__ float lq[YD][CO];
  __shared__ float lc[YD];
  ls[ty][c] = s; lq[ty][c] = q;
  if (c == 0) lc[ty] = cnt;
  __syncthreads();
  if (ty == 0) {
    #pragma unroll
    for (int i = 1; i < YD; i++) { s += ls[i][c]; q += lq[i][c]; }
    atomicAdd(&stats[c], s);
    atomicAdd(&stats[CO + c], q);
    if (c == 0) {
      float tc = 0.f;
      #pragma unroll
      for (int i = 0; i < YD; i++) tc += lc[i];
      atomicAdd(&stats[2*CO], tc);
    }
  }
}

// ---------------------------------------------------------------------------
template<int CO>
__global__ __launch_bounds__(256)
void bn_apply(float* __restrict__ x, const unsigned char* __restrict__ m,
              const float* __restrict__ stats, const float* __restrict__ g,
              const float* __restrict__ b, int nvox) {
  int idx = blockIdx.x * blockDim.x + threadIdx.x;
  int vox = idx / CO, c = idx % CO;
  if (vox >= nvox) return;
  float cnt   = fmaxf(stats[2*CO], 1.f);
  float mean  = stats[c] / cnt;
  float var   = stats[CO + c] / cnt - mean*mean;
  float scale = g[c] * rsqrtf(var + EPSV);
  float v = (x[idx] - mean) * scale + b[c];
  v = fmaxf(v, 0.f);
  bool act = m ? (m[vox] != 0) : true;
  x[idx] = act ? v : 0.f;
}

// ---------------------------------------------------------------------------
// BN apply + dual output: fp32 in place AND bf16 copy (for MFMA consumer).
// ---------------------------------------------------------------------------
template<int CO>
__global__ __launch_bounds__(256)
void bn_apply_bf(float* __restrict__ x, const unsigned char* __restrict__ m,
                 const float* __restrict__ stats, const float* __restrict__ g,
                 const float* __restrict__ b, unsigned short* __restrict__ xb,
                 int nvox) {
  int idx = blockIdx.x * blockDim.x + threadIdx.x;
  int vox = idx / CO, c = idx % CO;
  if (vox >= nvox) return;
  float cnt   = fmaxf(stats[2*CO], 1.f);
  float mean  = stats[c] / cnt;
  float var   = stats[CO + c] / cnt - mean*mean;
  float scale = g[c] * rsqrtf(var + EPSV);
  float v = (x[idx] - mean) * scale + b[c];
  v = fmaxf(v, 0.f);
  bool act = m ? (m[vox] != 0) : true;
  v = act ? v : 0.f;
  x[idx]  = v;
  xb[idx] = f2bf(v);
}

// ---------------------------------------------------------------------------
__global__ __launch_bounds__(256)
void write_out(const float* __restrict__ x, float* __restrict__ out) {
  int idx = blockIdx.x * blockDim.x + threadIdx.x;
  if (idx >= 64*11*5*25) return;
  int y = idx % 25; int t = idx / 25;
  int z = t % 5;  t /= 5;
  int wx = t % 11; int c = t / 11;
  out[idx] = x[(((z*25 + y)*11) + wx)*64 + c];
}

// ---------------------------------------------------------------------------
extern "C" void kernel_launch(void* const* d_in, const int* in_sizes, int n_in,
                              void* d_out, int out_size, void* d_ws, size_t ws_size,
                              hipStream_t stream) {
  const float* vf    = (const float*)d_in[0];
  const int*   coors = (const int*)d_in[1];
  int n = in_sizes[0] / 16;

  // dict order is INTERLEAVED: vf, coors, bs, shape, (w0,g0,b0), (w1,g1,b1), ...
  const float *w[9], *g[9], *b[9];
  for (int i = 0; i < 9; i++) {
    w[i] = (const float*)d_in[4 + 3*i];
    g[i] = (const float*)d_in[5 + 3*i];
    b[i] = (const float*)d_in[6 + 3*i];
  }
  float* out = (float*)d_out;

  char* wsb = (char*)d_ws;
  size_t off = 0;
  auto alloc = [&](size_t bytes) -> void* {
    void* p = wsb + off;
    off += (bytes + 255) & ~(size_t)255;
    return p;
  };
  // NOTE alloc order: grid0, fA, fB FIRST and contiguous — xB (bf16 input of
  // L3, 12.8 MB) overlays this 14.1 MB region; all grid0/fA/fB uses end
  // before bn_apply_bf(L2) writes xB.
  int*   grid0 = (int*)  alloc((size_t)40*200*200*4);
  float* fA    = (float*)alloc((size_t)n*16*4);
  float* fB    = (float*)alloc((size_t)n*16*4);
  float* wp    = (float*)alloc((size_t)454656*4);
  float* wq    = (float*)alloc((size_t)233472*4);
  unsigned short* wq3 = (unsigned short*)alloc((size_t)27648*2);
  float* dA    = (float*)alloc((size_t)20*100*100*32*4);
  float* dB    = (float*)alloc((size_t)20*100*100*32*4);
  unsigned char* m2 = (unsigned char*)alloc(20*100*100);
  unsigned char* m4 = (unsigned char*)alloc(10*50*50);
  unsigned char* m6 = (unsigned char*)alloc(5*25*24);
  unsigned char* m8 = (unsigned char*)alloc(5*25*11);
  float* stats = (float*)alloc((size_t)9*160*4);
  unsigned short* xB = (unsigned short*)grid0;   // overlay (12.8 MB < 14.1 MB)

  float* st[9];
  for (int i = 0; i < 9; i++) st[i] = stats + i*160;

  hipMemsetAsync(grid0, 0xFF, (size_t)40*200*200*4, stream);
  hipMemsetAsync(stats, 0, (size_t)9*160*4, stream);

  WPtrs wps; for (int i = 0; i < 9; i++) wps.w[i] = w[i];
  repack_w<<<idiv(454656,256), 256, 0, stream>>>(wps, wp);
  repack_wq<<<idiv(233472,256), 256, 0, stream>>>(w[6], w[7], w[8], wq);
  repack_w3b<<<idiv(27648,256), 256, 0, stream>>>(w[3], wq3);
  scatter_grid<<<idiv(n,256), 256, 0, stream>>>(coors, grid0, n);

  const int WO0=0, WO1=6912, WO2=13824, WO4=55296, WO5=110592;
  const int WQ6=0, WQ7=110592, WQ8=221184;

  // ---- L0, L1: sparse subm 16->16 ----
  subm16<<<idiv(n,256), 256, 0, stream>>>(vf, fA, coors, grid0, wp + WO0, n);
  bn_stats<16,16><<<imin(256, idiv(n,16)), dim3(16,16), 0, stream>>>(fA, nullptr, st[0], n);
  bn_apply<16><<<idiv(n*16,256), 256, 0, stream>>>(fA, nullptr, st[0], g[0], b[0], n);

  subm16<<<idiv(n,256), 256, 0, stream>>>(fA, fB, coors, grid0, wp + WO1, n);
  bn_stats<16,16><<<imin(256, idiv(n,16)), dim3(16,16), 0, stream>>>(fB, nullptr, st[1], n);
  bn_apply<16><<<idiv(n*16,256), 256, 0, stream>>>(fB, nullptr, st[1], g[1], b[1], n);

  // ---- L2: down 16->32 -> dense (20,100,100); bn emits fp32 + bf16 ----
  down16to32<<<dim3(idiv(200000,256),2), 256, 0, stream>>>(fB, grid0, dA, m2, wp + WO2);
  bn_stats<32,8><<<imin(256, idiv(200000,8)), dim3(32,8), 0, stream>>>(dA, m2, st[2], 200000);
  bn_apply_bf<32><<<idiv(200000*32,256), 256, 0, stream>>>(dA, m2, st[2], g[2], b[2], xB, 200000);

  // ---- L3: subm 32->32 dense, bf16 MFMA implicit-GEMM ----
  convm3<<<200000/64, 256, 0, stream>>>(xB, dB, wq3);
  bn_stats<32,8><<<imin(256, idiv(200000,8)), dim3(32,8), 0, stream>>>(dB, m2, st[3], 200000);
  bn_apply<32><<<idiv(200000*32,256), 256, 0, stream>>>(dB, m2, st[3], g[3], b[3], 200000);

  // ---- L4: down 32->64 -> (10,50,50), VT=64 (S=16,VX=4,CO2=4) + mask ----
  convg<20,100,100, 10,50,50, 32,64, 16,4,4, 3,3,3, 2,2,2, 1,1,1>
      <<<idiv(25000,64), 256, 0, stream>>>(dB, dA, wp + WO4);
  mask_down<20,100,100, 10,50,50, 3,3,3, 2,2,2, 1,1,1>
      <<<idiv(25000,256), 256, 0, stream>>>(m2, m4);
  bn_stats<64,4><<<imin(256, idiv(25000,4)), dim3(64,4), 0, stream>>>(dA, m4, st[4], 25000);
  bn_apply<64><<<idiv(25000*64,256), 256, 0, stream>>>(dA, m4, st[4], g[4], b[4], 25000);

  // ---- L5: subm 64->64, VT=64 (S=16,VX=4,CO2=4) ----
  convg<10,50,50, 10,50,50, 64,64, 16,4,4, 3,3,3, 1,1,1, 1,1,1>
      <<<idiv(25000,64), 256, 0, stream>>>(dA, dB, wp + WO5);
  bn_stats<64,4><<<imin(256, idiv(25000,4)), dim3(64,4), 0, stream>>>(dB, m4, st[5], 25000);
  bn_apply<64><<<idiv(25000*64,256), 256, 0, stream>>>(dB, m4, st[5], g[5], b[5], 25000);

  // ---- L6: down 64->64 s(2,2,2) p(1,1,0) -> (5,25,24), block-per-voxel ----
  convt<10,50,50, 5,25,24, 3,3,3, 2,2,2, 1,1,0>
      <<<3000, 256, 0, stream>>>(dB, dA, wq + WQ6);
  mask_down<10,50,50, 5,25,24, 3,3,3, 2,2,2, 1,1,0>
      <<<idiv(3000,256), 256, 0, stream>>>(m4, m6);
  bn_stats<64,4><<<imin(256, idiv(3000,4)), dim3(64,4), 0, stream>>>(dA, m6, st[6], 3000);
  bn_apply<64><<<idiv(3000*64,256), 256, 0, stream>>>(dA, m6, st[6], g[6], b[6], 3000);

  // ---- L7: subm 64->64, block-per-voxel ----
  convt<5,25,24, 5,25,24, 3,3,3, 1,1,1, 1,1,1>
      <<<3000, 256, 0, stream>>>(dA, dB, wq + WQ7);
  bn_stats<64,4><<<imin(256, idiv(3000,4)), dim3(64,4), 0, stream>>>(dB, m6, st[7], 3000);
  bn_apply<64><<<idiv(3000*64,256), 256, 0, stream>>>(dB, m6, st[7], g[7], b[7], 3000);

  // ---- L8: down 64->64 k(1,1,3) s(1,1,2) -> (5,25,11), block-per-voxel ----
  convt<5,25,24, 5,25,11, 1,1,3, 1,1,2, 0,0,0>
      <<<1375, 256, 0, stream>>>(dB, dA, wq + WQ8);
  mask_down<5,25,24, 5,25,11, 1,1,3, 1,1,2, 0,0,0>
      <<<idiv(1375,256), 256, 0, stream>>>(m6, m8);
  bn_stats<64,4><<<imin(256, idiv(1375,4)), dim3(64,4), 0, stream>>>(dA, m8, st[8], 1375);
  bn_apply<64><<<idiv(1375*64,256), 256, 0, stream>>>(dA, m8, st[8], g[8], b[8], 1375);

  write_out<<<idiv(88000,256), 256, 0, stream>>>(dA, out);
}

// Round 12
// 816.754 us; speedup vs baseline: 1.4777x; 1.2502x over previous
//
#include <hip/hip_runtime.h>
#include <cstddef>

#define EPSV 0.001f

static inline int idiv(int a, int b){ return (a + b - 1) / b; }
static inline int imin(int a, int b){ return a < b ? a : b; }

typedef __attribute__((ext_vector_type(8))) short short8b;
typedef __attribute__((ext_vector_type(4))) float floatx4;

// float -> bf16 round-to-nearest-even
static __device__ inline unsigned short f2bf(float f) {
  unsigned u = __float_as_uint(f);
  unsigned r = (u + 0x7FFFu + ((u >> 16) & 1u)) >> 16;
  return (unsigned short)r;
}

// ---------------------------------------------------------------------------
// Weight repack: w (CO,CI,kz,ky,kx) -> wp[(tap*CI+ci)*CO + co]
// ---------------------------------------------------------------------------
struct WPtrs { const float* w[9]; };

__global__ __launch_bounds__(256)
void repack_w(WPtrs ws, float* __restrict__ wp) {
  constexpr int off[10] = {0,6912,13824,27648,55296,110592,221184,331776,442368,454656};
  constexpr int COs[9] = {16,16,32,32,64,64,64,64,64};
  constexpr int CIs[9] = {16,16,16,32,32,64,64,64,64};
  constexpr int NTs[9] = {27,27,27,27,27,27,27,27,3};
  int idx = blockIdx.x * blockDim.x + threadIdx.x;
  if (idx >= off[9]) return;
  int L = 0;
  #pragma unroll
  for (int k = 0; k < 9; k++) if (idx >= off[k+1]) L = k + 1;
  int r  = idx - off[L];
  int CO = COs[L], CI = CIs[L], NT = NTs[L];
  int co = r % CO; int t = r / CO; int ci = t % CI; int tap = t / CI;
  wp[idx] = ws.w[L][(co*CI + ci)*NT + tap];
}

// ---------------------------------------------------------------------------
// Tail-layer weight repack: w (64,64,NT) -> wq[tap][ci_chunk(16)][co(64)][4]
// (ci = chunk*4 + j).  For fixed (tap,chunk) the 64 lanes' float4 chunks are
// CONTIGUOUS -> coalesced 1KB/wave weight loads in convt.
// Layers 6,7 (27 taps) and 8 (3 taps), concatenated.
// ---------------------------------------------------------------------------
__global__ __launch_bounds__(256)
void repack_wq(const float* __restrict__ w6, const float* __restrict__ w7,
               const float* __restrict__ w8, float* __restrict__ wq) {
  constexpr int N6 = 110592, N7 = 110592, N8 = 12288;
  int idx = blockIdx.x * blockDim.x + threadIdx.x;
  if (idx >= N6 + N7 + N8) return;
  const float* src; int r; int NT;
  if (idx < N6)            { src = w6; r = idx;          NT = 27; }
  else if (idx < N6 + N7)  { src = w7; r = idx - N6;     NT = 27; }
  else                     { src = w8; r = idx - N6 - N7; NT = 3; }
  int j = r & 3; int co = (r >> 2) & 63; int chunk = (r >> 8) & 15; int tap = r >> 12;
  int ci = chunk*4 + j;
  wq[idx] = src[(co*64 + ci)*NT + tap];
}

// ---------------------------------------------------------------------------
// L3 bf16 weight repack: w3 (32,32,3,3,3) -> wq3[(tap*32+co)*32+ci] (bf16)
// ---------------------------------------------------------------------------
__global__ __launch_bounds__(256)
void repack_w3b(const float* __restrict__ w3, unsigned short* __restrict__ wq3) {
  int idx = blockIdx.x * blockDim.x + threadIdx.x;
  if (idx >= 27648) return;
  int ci = idx % 32; int t = idx / 32; int co = t % 32; int tap = t / 32;
  wq3[idx] = f2bf(w3[(co*32 + ci)*27 + tap]);
}

// ---------------------------------------------------------------------------
__global__ __launch_bounds__(256)
void scatter_grid(const int* __restrict__ coors, int* __restrict__ grid, int n) {
  int i = blockIdx.x * blockDim.x + threadIdx.x;
  if (i >= n) return;
  int z = coors[4*i+1], y = coors[4*i+2], x = coors[4*i+3];
  grid[(z*200 + y)*200 + x] = i;
}

// ---------------------------------------------------------------------------
// Sparse submanifold 3x3x3 conv, 16->16, over active voxel list.
// ---------------------------------------------------------------------------
__global__ __launch_bounds__(256)
void subm16(const float* __restrict__ fin, float* __restrict__ fout,
            const int* __restrict__ coors, const int* __restrict__ grid,
            const float* __restrict__ wp, int n) {
  int i = blockIdx.x * blockDim.x + threadIdx.x;
  if (i >= n) return;
  int z = coors[4*i+1], y = coors[4*i+2], x = coors[4*i+3];
  float acc[16];
  #pragma unroll
  for (int c = 0; c < 16; c++) acc[c] = 0.f;
  for (int kz = 0; kz < 3; kz++) {
    int iz = z + kz - 1; if ((unsigned)iz >= 40u) continue;
    for (int ky = 0; ky < 3; ky++) {
      int iy = y + ky - 1; if ((unsigned)iy >= 200u) continue;
      for (int kx = 0; kx < 3; kx++) {
        int ix = x + kx - 1; if ((unsigned)ix >= 200u) continue;
        int j = grid[(iz*200 + iy)*200 + ix];
        if (j < 0) continue;
        int tap = (kz*3 + ky)*3 + kx;
        const float* fj = fin + (size_t)j*16;
        const float* wb = wp + tap*16*16;
        #pragma unroll
        for (int cq = 0; cq < 4; cq++) {
          float4 av = *reinterpret_cast<const float4*>(fj + cq*4);
          float aj[4] = {av.x, av.y, av.z, av.w};
          #pragma unroll
          for (int j4 = 0; j4 < 4; j4++) {
            #pragma unroll
            for (int c = 0; c < 16; c++) acc[c] += aj[j4] * wb[(cq*4+j4)*16 + c];
          }
        }
      }
    }
  }
  float* o = fout + (size_t)i*16;
  #pragma unroll
  for (int c = 0; c < 16; c++) o[c] = acc[c];
}

// ---------------------------------------------------------------------------
// L2: strided (2,2,2) pad(1,1,1) 3x3x3 conv 16->32, sparse -> dense
// channels-last (20,100,100,32) + new mask. COPT=16, grid.y=2.
// ---------------------------------------------------------------------------
__global__ __launch_bounds__(256)
void down16to32(const float* __restrict__ fin, const int* __restrict__ grid,
                float* __restrict__ out, unsigned char* __restrict__ mout,
                const float* __restrict__ wp) {
  constexpr int OD = 20, OH = 100, OW = 100, COPT = 16;
  int vox = blockIdx.x * blockDim.x + threadIdx.x;
  int cog = blockIdx.y;
  if (vox >= OD*OH*OW) return;
  int ox = vox % OW; int t = vox / OW; int oy = t % OH; int oz = t / OH;
  float acc[COPT];
  #pragma unroll
  for (int c = 0; c < COPT; c++) acc[c] = 0.f;
  bool any = false;
  for (int kz = 0; kz < 3; kz++) {
    int iz = oz*2 - 1 + kz; if ((unsigned)iz >= 40u) continue;
    for (int ky = 0; ky < 3; ky++) {
      int iy = oy*2 - 1 + ky; if ((unsigned)iy >= 200u) continue;
      for (int kx = 0; kx < 3; kx++) {
        int ix = ox*2 - 1 + kx; if ((unsigned)ix >= 200u) continue;
        int j = grid[(iz*200 + iy)*200 + ix];
        if (j < 0) continue;
        any = true;
        int tap = (kz*3 + ky)*3 + kx;
        const float* fj = fin + (size_t)j*16;
        const float* wb = wp + (size_t)tap*16*32 + cog*COPT;
        #pragma unroll
        for (int cq = 0; cq < 4; cq++) {
          float4 av = *reinterpret_cast<const float4*>(fj + cq*4);
          float aj[4] = {av.x, av.y, av.z, av.w};
          #pragma unroll
          for (int j4 = 0; j4 < 4; j4++) {
            #pragma unroll
            for (int c = 0; c < COPT; c++) acc[c] += aj[j4] * wb[(cq*4+j4)*32 + c];
          }
        }
      }
    }
  }
  float* o = out + (size_t)vox*32 + cog*COPT;
  #pragma unroll
  for (int c = 0; c < COPT; c++) o[c] = acc[c];
  if (cog == 0) mout[vox] = any ? 1 : 0;
}

// ---------------------------------------------------------------------------
// L3 bf16 MFMA implicit-GEMM subm conv 32->32 on (20,100,100).
// Block = 64 voxels x 32 co, 4 waves; wave w: voxels [w*16,w*16+16) x 32 co.
// ---------------------------------------------------------------------------
__global__ __launch_bounds__(256)
void convm3(const unsigned short* __restrict__ xb, float* __restrict__ out,
            const unsigned short* __restrict__ wq3) {
  constexpr int D = 20, H = 100, W = 100;
  constexpr int LDA = 40;
  __shared__ unsigned short a_lds[64 * LDA];
  __shared__ unsigned short w_lds[32 * LDA];

  const int tid  = threadIdx.x;
  const int lane = tid & 63;
  const int wv   = tid >> 6;
  const int vbase = blockIdx.x * 64;

  const int svox = tid >> 2, sq = tid & 3;
  int gv = vbase + svox;
  int sx = gv % W; int tt = gv / W; int sy = tt % H; int sz = tt / H;

  floatx4 acc0 = {0.f,0.f,0.f,0.f};
  floatx4 acc1 = {0.f,0.f,0.f,0.f};
  const int arow = wv*16 + (lane & 15);
  const int kc   = (lane >> 4) * 8;

  #pragma unroll 1
  for (int tap = 0; tap < 27; tap++) {
    int kz = tap / 9, r9 = tap % 9;
    int ky = r9 / 3, kx = r9 % 3;
    int iz = sz + kz - 1, iy = sy + ky - 1, ix = sx + kx - 1;
    bool ok = ((unsigned)iz < (unsigned)D) & ((unsigned)iy < (unsigned)H)
            & ((unsigned)ix < (unsigned)W);
    float4 av = make_float4(0.f,0.f,0.f,0.f);
    if (ok)
      av = *reinterpret_cast<const float4*>(
          xb + ((size_t)((iz*H + iy)*W + ix)*32 + sq*8));
    __syncthreads();  // previous iteration's MFMA reads done
    *reinterpret_cast<float4*>(&a_lds[svox*LDA + sq*8]) = av;
    if (tid < 128) {
      int co = tid >> 2, h = tid & 3;
      *reinterpret_cast<float4*>(&w_lds[co*LDA + h*8]) =
          *reinterpret_cast<const float4*>(wq3 + ((size_t)(tap*32 + co)*32 + h*8));
    }
    __syncthreads();
    short8b a  = *reinterpret_cast<const short8b*>(&a_lds[arow*LDA + kc]);
    short8b b0 = *reinterpret_cast<const short8b*>(&w_lds[(lane & 15)*LDA + kc]);
    short8b b1 = *reinterpret_cast<const short8b*>(&w_lds[(16 + (lane & 15))*LDA + kc]);
    acc0 = __builtin_amdgcn_mfma_f32_16x16x32_bf16(a, b0, acc0, 0, 0, 0);
    acc1 = __builtin_amdgcn_mfma_f32_16x16x32_bf16(a, b1, acc1, 0, 0, 0);
  }
  int orow = vbase + wv*16 + (lane >> 4) * 4;
  int ocol = lane & 15;
  #pragma unroll
  for (int rr = 0; rr < 4; rr++) {
    out[(size_t)(orow + rr)*32 + ocol]      = acc0[rr];
    out[(size_t)(orow + rr)*32 + 16 + ocol] = acc1[rr];
  }
}

// ---------------------------------------------------------------------------
// LDS implicit-GEMM dense conv, channels-last (generic, per-tap staging).
// ---------------------------------------------------------------------------
template<int ID,int IH,int IW,int OD,int OH,int OW,int CI,int CO,
         int S,int VX,int CO2,
         int KD,int KH,int KW,int SD,int SH,int SW,int PD,int PH,int PW>
__global__ __launch_bounds__(256)
void convg(const float* __restrict__ in, float* __restrict__ out,
           const float* __restrict__ wp) {
  constexpr int G    = 256 / S;
  static_assert(G * CO2 == CO, "co tiling mismatch");
  constexpr int VT   = S * VX;
  constexpr int NVOX = OD*OH*OW;
  __shared__ float a_lds[VT * CI];
  __shared__ float w_lds[CI * CO];

  const int g   = threadIdx.x % G;
  const int s   = threadIdx.x / G;
  const int co0 = g * CO2;
  const int vbase = blockIdx.x * VT;

  float acc[VX][CO2];
  #pragma unroll
  for (int u = 0; u < VX; u++)
    #pragma unroll
    for (int cc = 0; cc < CO2; cc++) acc[u][cc] = 0.f;

  constexpr int CI4N = CI / 4;
  constexpr int VST  = 256 / CI4N;
  const int sv  = threadIdx.x / CI4N;
  const int sc4 = threadIdx.x % CI4N;

  #pragma unroll 1
  for (int kz = 0; kz < KD; kz++) {
    #pragma unroll 1
    for (int ky = 0; ky < KH; ky++) {
      #pragma unroll 1
      for (int kx = 0; kx < KW; kx++) {
        __syncthreads();
        const float* wt = wp + (size_t)((kz*KH + ky)*KW + kx) * CI * CO;
        #pragma unroll
        for (int i = 0; i < CI*CO/4/256; i++) {
          int idx = threadIdx.x + i*256;
          *reinterpret_cast<float4*>(&w_lds[idx*4]) =
              *reinterpret_cast<const float4*>(wt + idx*4);
        }
        #pragma unroll
        for (int rsub = 0; rsub < VT/VST; rsub++) {
          int vox = rsub*VST + sv;
          int gv  = vbase + vox;
          int vc  = gv < NVOX ? gv : 0;
          int ox = vc % OW; int tt = vc / OW; int oy = tt % OH; int oz = tt / OH;
          int iz = oz*SD - PD + kz;
          int iy = oy*SH - PH + ky;
          int ix = ox*SW - PW + kx;
          bool ok = (gv < NVOX) & ((unsigned)iz < (unsigned)ID)
                  & ((unsigned)iy < (unsigned)IH) & ((unsigned)ix < (unsigned)IW);
          float4 v = make_float4(0.f,0.f,0.f,0.f);
          if (ok) {
            int ipos = (iz*IH + iy)*IW + ix;
            v = *reinterpret_cast<const float4*>(in + (size_t)ipos*CI + sc4*4);
          }
          int dw = vox*CI + ((sc4*4) ^ ((vox & 7) << 2));
          *reinterpret_cast<float4*>(&a_lds[dw]) = v;
        }
        __syncthreads();
        #pragma unroll
        for (int c4 = 0; c4 < CI/4; c4++) {
          float wr[4][CO2];
          #pragma unroll
          for (int jj = 0; jj < 4; jj++)
            #pragma unroll
            for (int q = 0; q < CO2/4; q++) {
              float4 wv = *reinterpret_cast<const float4*>(
                  &w_lds[(c4*4 + jj)*CO + co0 + q*4]);
              wr[jj][q*4+0] = wv.x; wr[jj][q*4+1] = wv.y;
              wr[jj][q*4+2] = wv.z; wr[jj][q*4+3] = wv.w;
            }
          #pragma unroll
          for (int u = 0; u < VX; u++) {
            int r = s + S*u;
            float4 a4 = *reinterpret_cast<const float4*>(
                &a_lds[r*CI + ((c4*4) ^ ((r & 7) << 2))]);
            float av[4] = {a4.x, a4.y, a4.z, a4.w};
            #pragma unroll
            for (int jj = 0; jj < 4; jj++)
              #pragma unroll
              for (int cc = 0; cc < CO2; cc++)
                acc[u][cc] += av[jj] * wr[jj][cc];
          }
        }
      }
    }
  }
  #pragma unroll
  for (int u = 0; u < VX; u++) {
    int gv = vbase + s + S*u;
    if (gv >= NVOX) continue;
    float* o = out + (size_t)gv*CO + co0;
    #pragma unroll
    for (int q = 0; q < CO2/4; q++) {
      float4 v = make_float4(acc[u][q*4+0], acc[u][q*4+1],
                             acc[u][q*4+2], acc[u][q*4+3]);
      *reinterpret_cast<float4*>(o + q*4) = v;
    }
  }
}

// ---------------------------------------------------------------------------
// Tail dense conv 64->64: ONE BLOCK PER OUTPUT VOXEL.
// 256 threads = 64 co-lanes x 4 ci-quarters. Weight layout
// [tap][chunk(16)][co(64)][4] -> per-instruction lane dim (co) contiguous,
// coalesced 1KB/wave weight loads.
// ---------------------------------------------------------------------------
template<int ID,int IH,int IW,int OD,int OH,int OW,
         int KD,int KH,int KW,int SD,int SH,int SW,int PD,int PH,int PW>
__global__ __launch_bounds__(256)
void convt(const float* __restrict__ in, float* __restrict__ out,
           const float* __restrict__ wq) {
  constexpr int NT = KD*KH*KW;
  constexpr int NG = (NT + 3) / 4;
  const int v    = blockIdx.x;
  const int lane = threadIdx.x & 63;
  const int q    = threadIdx.x >> 6;
  int ox = v % OW; int t = v / OW; int oy = t % OH; int oz = t / OH;

  __shared__ float a_lds[4][64];
  __shared__ float red[4][64];
  float acc = 0.f;

  #pragma unroll 1
  for (int tg = 0; tg < NG; tg++) {
    int tap = tg*4 + q;
    float val = 0.f;
    if (tap < NT) {
      int kz = tap / (KH*KW); int rr = tap % (KH*KW);
      int ky = rr / KW;       int kx = rr % KW;
      int iz = oz*SD - PD + kz, iy = oy*SH - PH + ky, ix = ox*SW - PW + kx;
      if ((unsigned)iz < (unsigned)ID && (unsigned)iy < (unsigned)IH &&
          (unsigned)ix < (unsigned)IW)
        val = in[(size_t)((iz*IH + iy)*IW + ix)*64 + lane];
    }
    __syncthreads();
    a_lds[q][lane] = val;
    __syncthreads();
    #pragma unroll
    for (int t4 = 0; t4 < 4; t4++) {
      int tap2 = tg*4 + t4;
      if (tap2 >= NT) break;
      #pragma unroll
      for (int c4 = 0; c4 < 4; c4++) {
        float4 w4 = *reinterpret_cast<const float4*>(
            wq + ((size_t)((tap2*16 + q*4 + c4)*64 + lane) * 4));
        acc += w4.x * a_lds[t4][q*16 + c4*4 + 0];
        acc += w4.y * a_lds[t4][q*16 + c4*4 + 1];
        acc += w4.z * a_lds[t4][q*16 + c4*4 + 2];
        acc += w4.w * a_lds[t4][q*16 + c4*4 + 3];
      }
    }
  }
  red[q][lane] = acc;
  __syncthreads();
  if (q == 0) {
    float s = red[0][lane] + red[1][lane] + red[2][lane] + red[3][lane];
    out[(size_t)v*64 + lane] = s;
  }
}

// ---------------------------------------------------------------------------
// Downsample mask: mout[v] = OR over taps of in-bounds min_.
// ---------------------------------------------------------------------------
template<int ID,int IH,int IW,int OD,int OH,int OW,int KD,int KH,int KW,
         int SD,int SH,int SW,int PD,int PH,int PW>
__global__ __launch_bounds__(256)
void mask_down(const unsigned char* __restrict__ min_, unsigned char* __restrict__ mout) {
  int v = blockIdx.x * blockDim.x + threadIdx.x;
  if (v >= OD*OH*OW) return;
  int ox = v % OW; int t = v / OW; int oy = t % OH; int oz = t / OH;
  bool any = false;
  for (int kz = 0; kz < KD; kz++) {
    int iz = oz*SD - PD + kz; if ((unsigned)iz >= (unsigned)ID) continue;
    for (int ky = 0; ky < KH; ky++) {
      int iy = oy*SH - PH + ky; if ((unsigned)iy >= (unsigned)IH) continue;
      for (int kx = 0; kx < KW; kx++) {
        int ix = ox*SW - PW + kx; if ((unsigned)ix >= (unsigned)IW) continue;
        any = any || (min_[(iz*IH + iy)*IW + ix] != 0);
      }
    }
  }
  mout[v] = any ? 1 : 0;
}

// ---------------------------------------------------------------------------
// Masked BN stats: per-channel sum, sumsq, count.
// ---------------------------------------------------------------------------
template<int CO, int YD>
__global__ void bn_stats(const float* __restrict__ x, const unsigned char* __restrict__ m,
                         float* __restrict__ stats, int nvox) {
  int c  = threadIdx.x;
  int ty = threadIdx.y;
  float s = 0.f, q = 0.f, cnt = 0.f;
  for (int vox = blockIdx.x*YD + ty; vox < nvox; vox += gridDim.x*YD) {
    bool act = m ? (m[vox] != 0) : true;
    if (act) {
      float v = x[(size_t)vox*CO + c];
      s += v; q += v*v; cnt += 1.f;
    }
  }
  __shared__ float ls[YD][CO];
  __shared__ float lq[YD][CO];
  __shared__ float lc[YD];
  ls[ty][c] = s; lq[ty][c] = q;
  if (c == 0) lc[ty] = cnt;
  __syncthreads();
  if (ty == 0) {
    #pragma unroll
    for (int i = 1; i < YD; i++) { s += ls[i][c]; q += lq[i][c]; }
    atomicAdd(&stats[c], s);
    atomicAdd(&stats[CO + c], q);
    if (c == 0) {
      float tc = 0.f;
      #pragma unroll
      for (int i = 0; i < YD; i++) tc += lc[i];
      atomicAdd(&stats[2*CO], tc);
    }
  }
}

// ---------------------------------------------------------------------------
template<int CO>
__global__ __launch_bounds__(256)
void bn_apply(float* __restrict__ x, const unsigned char* __restrict__ m,
              const float* __restrict__ stats, const float* __restrict__ g,
              const float* __restrict__ b, int nvox) {
  int idx = blockIdx.x * blockDim.x + threadIdx.x;
  int vox = idx / CO, c = idx % CO;
  if (vox >= nvox) return;
  float cnt   = fmaxf(stats[2*CO], 1.f);
  float mean  = stats[c] / cnt;
  float var   = stats[CO + c] / cnt - mean*mean;
  float scale = g[c] * rsqrtf(var + EPSV);
  float v = (x[idx] - mean) * scale + b[c];
  v = fmaxf(v, 0.f);
  bool act = m ? (m[vox] != 0) : true;
  x[idx] = act ? v : 0.f;
}

// ---------------------------------------------------------------------------
// BN apply + dual output: fp32 in place AND bf16 copy (for MFMA consumer).
// ---------------------------------------------------------------------------
template<int CO>
__global__ __launch_bounds__(256)
void bn_apply_bf(float* __restrict__ x, const unsigned char* __restrict__ m,
                 const float* __restrict__ stats, const float* __restrict__ g,
                 const float* __restrict__ b, unsigned short* __restrict__ xb,
                 int nvox) {
  int idx = blockIdx.x * blockDim.x + threadIdx.x;
  int vox = idx / CO, c = idx % CO;
  if (vox >= nvox) return;
  float cnt   = fmaxf(stats[2*CO], 1.f);
  float mean  = stats[c] / cnt;
  float var   = stats[CO + c] / cnt - mean*mean;
  float scale = g[c] * rsqrtf(var + EPSV);
  float v = (x[idx] - mean) * scale + b[c];
  v = fmaxf(v, 0.f);
  bool act = m ? (m[vox] != 0) : true;
  v = act ? v : 0.f;
  x[idx]  = v;
  xb[idx] = f2bf(v);
}

// ---------------------------------------------------------------------------
__global__ __launch_bounds__(256)
void write_out(const float* __restrict__ x, float* __restrict__ out) {
  int idx = blockIdx.x * blockDim.x + threadIdx.x;
  if (idx >= 64*11*5*25) return;
  int y = idx % 25; int t = idx / 25;
  int z = t % 5;  t /= 5;
  int wx = t % 11; int c = t / 11;
  out[idx] = x[(((z*25 + y)*11) + wx)*64 + c];
}

// ---------------------------------------------------------------------------
extern "C" void kernel_launch(void* const* d_in, const int* in_sizes, int n_in,
                              void* d_out, int out_size, void* d_ws, size_t ws_size,
                              hipStream_t stream) {
  const float* vf    = (const float*)d_in[0];
  const int*   coors = (const int*)d_in[1];
  int n = in_sizes[0] / 16;

  // dict order is INTERLEAVED: vf, coors, bs, shape, (w0,g0,b0), (w1,g1,b1), ...
  const float *w[9], *g[9], *b[9];
  for (int i = 0; i < 9; i++) {
    w[i] = (const float*)d_in[4 + 3*i];
    g[i] = (const float*)d_in[5 + 3*i];
    b[i] = (const float*)d_in[6 + 3*i];
  }
  float* out = (float*)d_out;

  char* wsb = (char*)d_ws;
  size_t off = 0;
  auto alloc = [&](size_t bytes) -> void* {
    void* p = wsb + off;
    off += (bytes + 255) & ~(size_t)255;
    return p;
  };
  // NOTE alloc order: grid0, fA, fB FIRST and contiguous — xB (bf16 input of
  // L3, 12.8 MB) overlays this 14.1 MB region; all grid0/fA/fB uses end
  // before bn_apply_bf(L2) writes xB.
  int*   grid0 = (int*)  alloc((size_t)40*200*200*4);
  float* fA    = (float*)alloc((size_t)n*16*4);
  float* fB    = (float*)alloc((size_t)n*16*4);
  float* wp    = (float*)alloc((size_t)454656*4);
  float* wq    = (float*)alloc((size_t)233472*4);
  unsigned short* wq3 = (unsigned short*)alloc((size_t)27648*2);
  float* dA    = (float*)alloc((size_t)20*100*100*32*4);
  float* dB    = (float*)alloc((size_t)20*100*100*32*4);
  unsigned char* m2 = (unsigned char*)alloc(20*100*100);
  unsigned char* m4 = (unsigned char*)alloc(10*50*50);
  unsigned char* m6 = (unsigned char*)alloc(5*25*24);
  unsigned char* m8 = (unsigned char*)alloc(5*25*11);
  float* stats = (float*)alloc((size_t)9*160*4);
  unsigned short* xB = (unsigned short*)grid0;   // overlay (12.8 MB < 14.1 MB)

  float* st[9];
  for (int i = 0; i < 9; i++) st[i] = stats + i*160;

  hipMemsetAsync(grid0, 0xFF, (size_t)40*200*200*4, stream);
  hipMemsetAsync(stats, 0, (size_t)9*160*4, stream);

  WPtrs wps; for (int i = 0; i < 9; i++) wps.w[i] = w[i];
  repack_w<<<idiv(454656,256), 256, 0, stream>>>(wps, wp);
  repack_wq<<<idiv(233472,256), 256, 0, stream>>>(w[6], w[7], w[8], wq);
  repack_w3b<<<idiv(27648,256), 256, 0, stream>>>(w[3], wq3);
  scatter_grid<<<idiv(n,256), 256, 0, stream>>>(coors, grid0, n);

  const int WO0=0, WO1=6912, WO2=13824, WO4=55296, WO5=110592;
  const int WQ6=0, WQ7=110592, WQ8=221184;

  // ---- L0, L1: sparse subm 16->16 ----
  subm16<<<idiv(n,256), 256, 0, stream>>>(vf, fA, coors, grid0, wp + WO0, n);
  bn_stats<16,16><<<imin(256, idiv(n,16)), dim3(16,16), 0, stream>>>(fA, nullptr, st[0], n);
  bn_apply<16><<<idiv(n*16,256), 256, 0, stream>>>(fA, nullptr, st[0], g[0], b[0], n);

  subm16<<<idiv(n,256), 256, 0, stream>>>(fA, fB, coors, grid0, wp + WO1, n);
  bn_stats<16,16><<<imin(256, idiv(n,16)), dim3(16,16), 0, stream>>>(fB, nullptr, st[1], n);
  bn_apply<16><<<idiv(n*16,256), 256, 0, stream>>>(fB, nullptr, st[1], g[1], b[1], n);

  // ---- L2: down 16->32 -> dense (20,100,100); bn emits fp32 + bf16 ----
  down16to32<<<dim3(idiv(200000,256),2), 256, 0, stream>>>(fB, grid0, dA, m2, wp + WO2);
  bn_stats<32,8><<<imin(256, idiv(200000,8)), dim3(32,8), 0, stream>>>(dA, m2, st[2], 200000);
  bn_apply_bf<32><<<idiv(200000*32,256), 256, 0, stream>>>(dA, m2, st[2], g[2], b[2], xB, 200000);

  // ---- L3: subm 32->32 dense, bf16 MFMA implicit-GEMM ----
  convm3<<<200000/64, 256, 0, stream>>>(xB, dB, wq3);
  bn_stats<32,8><<<imin(256, idiv(200000,8)), dim3(32,8), 0, stream>>>(dB, m2, st[3], 200000);
  bn_apply<32><<<idiv(200000*32,256), 256, 0, stream>>>(dB, m2, st[3], g[3], b[3], 200000);

  // ---- L4: down 32->64 -> (10,50,50), VT=64 (S=16,VX=4,CO2=4) + mask ----
  convg<20,100,100, 10,50,50, 32,64, 16,4,4, 3,3,3, 2,2,2, 1,1,1>
      <<<idiv(25000,64), 256, 0, stream>>>(dB, dA, wp + WO4);
  mask_down<20,100,100, 10,50,50, 3,3,3, 2,2,2, 1,1,1>
      <<<idiv(25000,256), 256, 0, stream>>>(m2, m4);
  bn_stats<64,4><<<imin(256, idiv(25000,4)), dim3(64,4), 0, stream>>>(dA, m4, st[4], 25000);
  bn_apply<64><<<idiv(25000*64,256), 256, 0, stream>>>(dA, m4, st[4], g[4], b[4], 25000);

  // ---- L5: subm 64->64, VT=64 (S=16,VX=4,CO2=4) ----
  convg<10,50,50, 10,50,50, 64,64, 16,4,4, 3,3,3, 1,1,1, 1,1,1>
      <<<idiv(25000,64), 256, 0, stream>>>(dA, dB, wp + WO5);
  bn_stats<64,4><<<imin(256, idiv(25000,4)), dim3(64,4), 0, stream>>>(dB, m4, st[5], 25000);
  bn_apply<64><<<idiv(25000*64,256), 256, 0, stream>>>(dB, m4, st[5], g[5], b[5], 25000);

  // ---- L6: down 64->64 s(2,2,2) p(1,1,0) -> (5,25,24), block-per-voxel ----
  convt<10,50,50, 5,25,24, 3,3,3, 2,2,2, 1,1,0>
      <<<3000, 256, 0, stream>>>(dB, dA, wq + WQ6);
  mask_down<10,50,50, 5,25,24, 3,3,3, 2,2,2, 1,1,0>
      <<<idiv(3000,256), 256, 0, stream>>>(m4, m6);
  bn_stats<64,4><<<imin(256, idiv(3000,4)), dim3(64,4), 0, stream>>>(dA, m6, st[6], 3000);
  bn_apply<64><<<idiv(3000*64,256), 256, 0, stream>>>(dA, m6, st[6], g[6], b[6], 3000);

  // ---- L7: subm 64->64, block-per-voxel ----
  convt<5,25,24, 5,25,24, 3,3,3, 1,1,1, 1,1,1>
      <<<3000, 256, 0, stream>>>(dA, dB, wq + WQ7);
  bn_stats<64,4><<<imin(256, idiv(3000,4)), dim3(64,4), 0, stream>>>(dB, m6, st[7], 3000);
  bn_apply<64><<<idiv(3000*64,256), 256, 0, stream>>>(dB, m6, st[7], g[7], b[7], 3000);

  // ---- L8: down 64->64 k(1,1,3) s(1,1,2) -> (5,25,11), block-per-voxel ----
  convt<5,25,24, 5,25,11, 1,1,3, 1,1,2, 0,0,0>
      <<<1375, 256, 0, stream>>>(dB, dA, wq + WQ8);
  mask_down<5,25,24, 5,25,11, 1,1,3, 1,1,2, 0,0,0>
      <<<idiv(1375,256), 256, 0, stream>>>(m6, m8);
  bn_stats<64,4><<<imin(256, idiv(1375,4)), dim3(64,4), 0, stream>>>(dA, m8, st[8], 1375);
  bn_apply<64><<<idiv(1375*64,256), 256, 0, stream>>>(dA, m8, st[8], g[8], b[8], 1375);

  write_out<<<idiv(88000,256), 256, 0, stream>>>(dA, out);
}

// Round 13
// 710.897 us; speedup vs baseline: 1.6978x; 1.1489x over previous
//
#include <hip/hip_runtime.h>
#include <cstddef>

#define EPSV 0.001f

static inline int idiv(int a, int b){ return (a + b - 1) / b; }
static inline int imin(int a, int b){ return a < b ? a : b; }

typedef __attribute__((ext_vector_type(8))) short short8b;
typedef __attribute__((ext_vector_type(4))) float floatx4;

// float -> bf16 round-to-nearest-even
static __device__ inline unsigned short f2bf(float f) {
  unsigned u = __float_as_uint(f);
  unsigned r = (u + 0x7FFFu + ((u >> 16) & 1u)) >> 16;
  return (unsigned short)r;
}

// ---------------------------------------------------------------------------
// Weight repack: w (CO,CI,kz,ky,kx) -> wp[(tap*CI+ci)*CO + co]
// (used by subm16 L0/L1 and down16to32 L2)
// ---------------------------------------------------------------------------
struct WPtrs { const float* w[9]; };

__global__ __launch_bounds__(256)
void repack_w(WPtrs ws, float* __restrict__ wp) {
  constexpr int off[10] = {0,6912,13824,27648,55296,110592,221184,331776,442368,454656};
  constexpr int COs[9] = {16,16,32,32,64,64,64,64,64};
  constexpr int CIs[9] = {16,16,16,32,32,64,64,64,64};
  constexpr int NTs[9] = {27,27,27,27,27,27,27,27,3};
  int idx = blockIdx.x * blockDim.x + threadIdx.x;
  if (idx >= off[9]) return;
  int L = 0;
  #pragma unroll
  for (int k = 0; k < 9; k++) if (idx >= off[k+1]) L = k + 1;
  int r  = idx - off[L];
  int CO = COs[L], CI = CIs[L], NT = NTs[L];
  int co = r % CO; int t = r / CO; int ci = t % CI; int tap = t / CI;
  wp[idx] = ws.w[L][(co*CI + ci)*NT + tap];
}

// ---------------------------------------------------------------------------
// Tail-layer weight repack: w (64,64,NT) -> wq[tap][ci_chunk(16)][co(64)][4]
// ---------------------------------------------------------------------------
__global__ __launch_bounds__(256)
void repack_wq(const float* __restrict__ w6, const float* __restrict__ w7,
               const float* __restrict__ w8, float* __restrict__ wq) {
  constexpr int N6 = 110592, N7 = 110592, N8 = 12288;
  int idx = blockIdx.x * blockDim.x + threadIdx.x;
  if (idx >= N6 + N7 + N8) return;
  const float* src; int r; int NT;
  if (idx < N6)            { src = w6; r = idx;          NT = 27; }
  else if (idx < N6 + N7)  { src = w7; r = idx - N6;     NT = 27; }
  else                     { src = w8; r = idx - N6 - N7; NT = 3; }
  int j = r & 3; int co = (r >> 2) & 63; int chunk = (r >> 8) & 15; int tap = r >> 12;
  int ci = chunk*4 + j;
  wq[idx] = src[(co*64 + ci)*NT + tap];
}

// ---------------------------------------------------------------------------
// L3 bf16 weight repack: w3 (32,32,3,3,3) -> wq3[(tap*32+co)*32+ci] (bf16)
// ---------------------------------------------------------------------------
__global__ __launch_bounds__(256)
void repack_w3b(const float* __restrict__ w3, unsigned short* __restrict__ wq3) {
  int idx = blockIdx.x * blockDim.x + threadIdx.x;
  if (idx >= 27648) return;
  int ci = idx % 32; int t = idx / 32; int co = t % 32; int tap = t / 32;
  wq3[idx] = f2bf(w3[(co*32 + ci)*27 + tap]);
}

// ---------------------------------------------------------------------------
// L4/L5 bf16 weight repack -> [tap][co][ci] bf16.
// w4 (64,32,27): 55296 elems; w5 (64,64,27): 110592 elems.
// ---------------------------------------------------------------------------
__global__ __launch_bounds__(256)
void repack_wmb(const float* __restrict__ w4, const float* __restrict__ w5,
                unsigned short* __restrict__ q4, unsigned short* __restrict__ q5) {
  int idx = blockIdx.x * blockDim.x + threadIdx.x;
  if (idx < 55296) {
    int ci = idx % 32; int t = idx / 32; int co = t % 64; int tap = t / 64;
    q4[idx] = f2bf(w4[(co*32 + ci)*27 + tap]);
  } else if (idx < 55296 + 110592) {
    int r = idx - 55296;
    int ci = r % 64; int t = r / 64; int co = t % 64; int tap = t / 64;
    q5[r] = f2bf(w5[(co*64 + ci)*27 + tap]);
  }
}

// ---------------------------------------------------------------------------
__global__ __launch_bounds__(256)
void scatter_grid(const int* __restrict__ coors, int* __restrict__ grid, int n) {
  int i = blockIdx.x * blockDim.x + threadIdx.x;
  if (i >= n) return;
  int z = coors[4*i+1], y = coors[4*i+2], x = coors[4*i+3];
  grid[(z*200 + y)*200 + x] = i;
}

// ---------------------------------------------------------------------------
// Sparse submanifold 3x3x3 conv, 16->16, over active voxel list.
// ---------------------------------------------------------------------------
__global__ __launch_bounds__(256)
void subm16(const float* __restrict__ fin, float* __restrict__ fout,
            const int* __restrict__ coors, const int* __restrict__ grid,
            const float* __restrict__ wp, int n) {
  int i = blockIdx.x * blockDim.x + threadIdx.x;
  if (i >= n) return;
  int z = coors[4*i+1], y = coors[4*i+2], x = coors[4*i+3];
  float acc[16];
  #pragma unroll
  for (int c = 0; c < 16; c++) acc[c] = 0.f;
  for (int kz = 0; kz < 3; kz++) {
    int iz = z + kz - 1; if ((unsigned)iz >= 40u) continue;
    for (int ky = 0; ky < 3; ky++) {
      int iy = y + ky - 1; if ((unsigned)iy >= 200u) continue;
      for (int kx = 0; kx < 3; kx++) {
        int ix = x + kx - 1; if ((unsigned)ix >= 200u) continue;
        int j = grid[(iz*200 + iy)*200 + ix];
        if (j < 0) continue;
        int tap = (kz*3 + ky)*3 + kx;
        const float* fj = fin + (size_t)j*16;
        const float* wb = wp + tap*16*16;
        #pragma unroll
        for (int cq = 0; cq < 4; cq++) {
          float4 av = *reinterpret_cast<const float4*>(fj + cq*4);
          float aj[4] = {av.x, av.y, av.z, av.w};
          #pragma unroll
          for (int j4 = 0; j4 < 4; j4++) {
            #pragma unroll
            for (int c = 0; c < 16; c++) acc[c] += aj[j4] * wb[(cq*4+j4)*16 + c];
          }
        }
      }
    }
  }
  float* o = fout + (size_t)i*16;
  #pragma unroll
  for (int c = 0; c < 16; c++) o[c] = acc[c];
}

// ---------------------------------------------------------------------------
// L2: strided (2,2,2) pad(1,1,1) 3x3x3 conv 16->32, sparse -> dense
// channels-last (20,100,100,32) + new mask. COPT=16, grid.y=2.
// ---------------------------------------------------------------------------
__global__ __launch_bounds__(256)
void down16to32(const float* __restrict__ fin, const int* __restrict__ grid,
                float* __restrict__ out, unsigned char* __restrict__ mout,
                const float* __restrict__ wp) {
  constexpr int OD = 20, OH = 100, OW = 100, COPT = 16;
  int vox = blockIdx.x * blockDim.x + threadIdx.x;
  int cog = blockIdx.y;
  if (vox >= OD*OH*OW) return;
  int ox = vox % OW; int t = vox / OW; int oy = t % OH; int oz = t / OH;
  float acc[COPT];
  #pragma unroll
  for (int c = 0; c < COPT; c++) acc[c] = 0.f;
  bool any = false;
  for (int kz = 0; kz < 3; kz++) {
    int iz = oz*2 - 1 + kz; if ((unsigned)iz >= 40u) continue;
    for (int ky = 0; ky < 3; ky++) {
      int iy = oy*2 - 1 + ky; if ((unsigned)iy >= 200u) continue;
      for (int kx = 0; kx < 3; kx++) {
        int ix = ox*2 - 1 + kx; if ((unsigned)ix >= 200u) continue;
        int j = grid[(iz*200 + iy)*200 + ix];
        if (j < 0) continue;
        any = true;
        int tap = (kz*3 + ky)*3 + kx;
        const float* fj = fin + (size_t)j*16;
        const float* wb = wp + (size_t)tap*16*32 + cog*COPT;
        #pragma unroll
        for (int cq = 0; cq < 4; cq++) {
          float4 av = *reinterpret_cast<const float4*>(fj + cq*4);
          float aj[4] = {av.x, av.y, av.z, av.w};
          #pragma unroll
          for (int j4 = 0; j4 < 4; j4++) {
            #pragma unroll
            for (int c = 0; c < COPT; c++) acc[c] += aj[j4] * wb[(cq*4+j4)*32 + c];
          }
        }
      }
    }
  }
  float* o = out + (size_t)vox*32 + cog*COPT;
  #pragma unroll
  for (int c = 0; c < COPT; c++) o[c] = acc[c];
  if (cog == 0) mout[vox] = any ? 1 : 0;
}

// ---------------------------------------------------------------------------
// L3 bf16 MFMA implicit-GEMM subm conv 32->32 on (20,100,100).
// (proven Round 11; unchanged)
// ---------------------------------------------------------------------------
__global__ __launch_bounds__(256)
void convm3(const unsigned short* __restrict__ xb, float* __restrict__ out,
            const unsigned short* __restrict__ wq3) {
  constexpr int D = 20, H = 100, W = 100;
  constexpr int LDA = 40;
  __shared__ unsigned short a_lds[64 * LDA];
  __shared__ unsigned short w_lds[32 * LDA];

  const int tid  = threadIdx.x;
  const int lane = tid & 63;
  const int wv   = tid >> 6;
  const int vbase = blockIdx.x * 64;

  const int svox = tid >> 2, sq = tid & 3;
  int gv = vbase + svox;
  int sx = gv % W; int tt = gv / W; int sy = tt % H; int sz = tt / H;

  floatx4 acc0 = {0.f,0.f,0.f,0.f};
  floatx4 acc1 = {0.f,0.f,0.f,0.f};
  const int arow = wv*16 + (lane & 15);
  const int kc   = (lane >> 4) * 8;

  #pragma unroll 1
  for (int tap = 0; tap < 27; tap++) {
    int kz = tap / 9, r9 = tap % 9;
    int ky = r9 / 3, kx = r9 % 3;
    int iz = sz + kz - 1, iy = sy + ky - 1, ix = sx + kx - 1;
    bool ok = ((unsigned)iz < (unsigned)D) & ((unsigned)iy < (unsigned)H)
            & ((unsigned)ix < (unsigned)W);
    float4 av = make_float4(0.f,0.f,0.f,0.f);
    if (ok)
      av = *reinterpret_cast<const float4*>(
          xb + ((size_t)((iz*H + iy)*W + ix)*32 + sq*8));
    __syncthreads();  // previous iteration's MFMA reads done
    *reinterpret_cast<float4*>(&a_lds[svox*LDA + sq*8]) = av;
    if (tid < 128) {
      int co = tid >> 2, h = tid & 3;
      *reinterpret_cast<float4*>(&w_lds[co*LDA + h*8]) =
          *reinterpret_cast<const float4*>(wq3 + ((size_t)(tap*32 + co)*32 + h*8));
    }
    __syncthreads();
    short8b a  = *reinterpret_cast<const short8b*>(&a_lds[arow*LDA + kc]);
    short8b b0 = *reinterpret_cast<const short8b*>(&w_lds[(lane & 15)*LDA + kc]);
    short8b b1 = *reinterpret_cast<const short8b*>(&w_lds[(16 + (lane & 15))*LDA + kc]);
    acc0 = __builtin_amdgcn_mfma_f32_16x16x32_bf16(a, b0, acc0, 0, 0, 0);
    acc1 = __builtin_amdgcn_mfma_f32_16x16x32_bf16(a, b1, acc1, 0, 0, 0);
  }
  int orow = vbase + wv*16 + (lane >> 4) * 4;
  int ocol = lane & 15;
  #pragma unroll
  for (int rr = 0; rr < 4; rr++) {
    out[(size_t)(orow + rr)*32 + ocol]      = acc0[rr];
    out[(size_t)(orow + rr)*32 + 16 + ocol] = acc1[rr];
  }
}

// ---------------------------------------------------------------------------
// Generalized bf16 MFMA implicit-GEMM 3x3x3 conv, CI in {32,64}, CO=64.
// Block = 64 output voxels x 64 co, 4 waves; wave w: voxels [w*16,w*16+16).
// Per tap: prefetch A/W to regs, stage LDS, 4 n-tiles x (CI/32) k-chunks MFMA.
// Same fragment layout as convm3 (verified).  Tail blocks guarded.
// ---------------------------------------------------------------------------
template<int ID,int IH,int IW,int OD,int OH,int OW,int CI,
         int SD,int SH,int SW,int PD,int PH,int PW>
__global__ __launch_bounds__(256)
void convm(const unsigned short* __restrict__ xb, float* __restrict__ out,
           const unsigned short* __restrict__ wb) {
  constexpr int CO  = 64;
  constexpr int NVO = OD*OH*OW;
  constexpr int LDA = CI + 8;           // ushort stride; mult of 8 -> 16B align
  constexpr int NCH = CI / 32;          // k-chunks per tap
  constexpr int CPR = CI / 8;           // float4 chunks per row
  constexpr int AROWS = 256 / CPR;      // A rows staged per pass
  constexpr int APASS = 64 / AROWS;     // 1 (CI=32) or 2 (CI=64)
  constexpr int WPASS = CO / AROWS;     // 1 (CI=32) or 2 (CI=64)
  __shared__ unsigned short a_lds[64 * LDA];
  __shared__ unsigned short w_lds[CO * LDA];

  const int tid  = threadIdx.x;
  const int lane = tid & 63;
  const int wv   = tid >> 6;
  const int vbase = blockIdx.x * 64;

  const int sva = tid / CPR;            // staging row
  const int sqa = tid % CPR;            // staging chunk

  floatx4 acc0 = {0.f,0.f,0.f,0.f};
  floatx4 acc1 = {0.f,0.f,0.f,0.f};
  floatx4 acc2 = {0.f,0.f,0.f,0.f};
  floatx4 acc3 = {0.f,0.f,0.f,0.f};
  const int arow = wv*16 + (lane & 15);
  const int kq   = (lane >> 4) * 8;

  // per-pass staged voxel coords (fixed across taps)
  int sx[APASS], sy[APASS], sz[APASS]; bool sval[APASS];
  #pragma unroll
  for (int p = 0; p < APASS; p++) {
    int row = p*AROWS + sva;
    int gv  = vbase + row;
    sval[p] = (gv < NVO);
    int gvc = sval[p] ? gv : 0;
    sx[p] = gvc % OW; int tt = gvc / OW; sy[p] = tt % OH; sz[p] = tt / OH;
  }

  #pragma unroll 1
  for (int tap = 0; tap < 27; tap++) {
    int kz = tap / 9, r9 = tap % 9;
    int ky = r9 / 3, kx = r9 % 3;
    // ---- prefetch to regs ----
    float4 avr[APASS];
    #pragma unroll
    for (int p = 0; p < APASS; p++) {
      int iz = sz[p]*SD - PD + kz, iy = sy[p]*SH - PH + ky, ix = sx[p]*SW - PW + kx;
      bool ok = sval[p] & ((unsigned)iz < (unsigned)ID)
              & ((unsigned)iy < (unsigned)IH) & ((unsigned)ix < (unsigned)IW);
      avr[p] = make_float4(0.f,0.f,0.f,0.f);
      if (ok)
        avr[p] = *reinterpret_cast<const float4*>(
            xb + ((size_t)((iz*IH + iy)*IW + ix)*CI + sqa*8));
    }
    float4 wvr[WPASS];
    #pragma unroll
    for (int p = 0; p < WPASS; p++) {
      int row = p*AROWS + sva;
      wvr[p] = *reinterpret_cast<const float4*>(
          wb + ((size_t)(tap*CO + row)*CI + sqa*8));
    }
    __syncthreads();  // previous iteration's MFMA reads done
    #pragma unroll
    for (int p = 0; p < APASS; p++)
      *reinterpret_cast<float4*>(&a_lds[(p*AROWS + sva)*LDA + sqa*8]) = avr[p];
    #pragma unroll
    for (int p = 0; p < WPASS; p++)
      *reinterpret_cast<float4*>(&w_lds[(p*AROWS + sva)*LDA + sqa*8]) = wvr[p];
    __syncthreads();
    // ---- MFMA ----
    #pragma unroll
    for (int c = 0; c < NCH; c++) {
      short8b a = *reinterpret_cast<const short8b*>(&a_lds[arow*LDA + c*32 + kq]);
      short8b b0 = *reinterpret_cast<const short8b*>(&w_lds[( 0 + (lane&15))*LDA + c*32 + kq]);
      short8b b1 = *reinterpret_cast<const short8b*>(&w_lds[(16 + (lane&15))*LDA + c*32 + kq]);
      short8b b2 = *reinterpret_cast<const short8b*>(&w_lds[(32 + (lane&15))*LDA + c*32 + kq]);
      short8b b3 = *reinterpret_cast<const short8b*>(&w_lds[(48 + (lane&15))*LDA + c*32 + kq]);
      acc0 = __builtin_amdgcn_mfma_f32_16x16x32_bf16(a, b0, acc0, 0, 0, 0);
      acc1 = __builtin_amdgcn_mfma_f32_16x16x32_bf16(a, b1, acc1, 0, 0, 0);
      acc2 = __builtin_amdgcn_mfma_f32_16x16x32_bf16(a, b2, acc2, 0, 0, 0);
      acc3 = __builtin_amdgcn_mfma_f32_16x16x32_bf16(a, b3, acc3, 0, 0, 0);
    }
  }
  int orow = vbase + wv*16 + (lane >> 4) * 4;
  int ocol = lane & 15;
  #pragma unroll
  for (int rr = 0; rr < 4; rr++) {
    if (orow + rr < NVO) {
      float* o = out + (size_t)(orow + rr)*CO;
      o[ 0 + ocol] = acc0[rr];
      o[16 + ocol] = acc1[rr];
      o[32 + ocol] = acc2[rr];
      o[48 + ocol] = acc3[rr];
    }
  }
}

// ---------------------------------------------------------------------------
// Tail dense conv 64->64: ONE BLOCK PER OUTPUT VOXEL (coalesced wq layout).
// ---------------------------------------------------------------------------
template<int ID,int IH,int IW,int OD,int OH,int OW,
         int KD,int KH,int KW,int SD,int SH,int SW,int PD,int PH,int PW>
__global__ __launch_bounds__(256)
void convt(const float* __restrict__ in, float* __restrict__ out,
           const float* __restrict__ wq) {
  constexpr int NT = KD*KH*KW;
  constexpr int NG = (NT + 3) / 4;
  const int v    = blockIdx.x;
  const int lane = threadIdx.x & 63;
  const int q    = threadIdx.x >> 6;
  int ox = v % OW; int t = v / OW; int oy = t % OH; int oz = t / OH;

  __shared__ float a_lds[4][64];
  __shared__ float red[4][64];
  float acc = 0.f;

  #pragma unroll 1
  for (int tg = 0; tg < NG; tg++) {
    int tap = tg*4 + q;
    float val = 0.f;
    if (tap < NT) {
      int kz = tap / (KH*KW); int rr = tap % (KH*KW);
      int ky = rr / KW;       int kx = rr % KW;
      int iz = oz*SD - PD + kz, iy = oy*SH - PH + ky, ix = ox*SW - PW + kx;
      if ((unsigned)iz < (unsigned)ID && (unsigned)iy < (unsigned)IH &&
          (unsigned)ix < (unsigned)IW)
        val = in[(size_t)((iz*IH + iy)*IW + ix)*64 + lane];
    }
    __syncthreads();
    a_lds[q][lane] = val;
    __syncthreads();
    #pragma unroll
    for (int t4 = 0; t4 < 4; t4++) {
      int tap2 = tg*4 + t4;
      if (tap2 >= NT) break;
      #pragma unroll
      for (int c4 = 0; c4 < 4; c4++) {
        float4 w4 = *reinterpret_cast<const float4*>(
            wq + ((size_t)((tap2*16 + q*4 + c4)*64 + lane) * 4));
        acc += w4.x * a_lds[t4][q*16 + c4*4 + 0];
        acc += w4.y * a_lds[t4][q*16 + c4*4 + 1];
        acc += w4.z * a_lds[t4][q*16 + c4*4 + 2];
        acc += w4.w * a_lds[t4][q*16 + c4*4 + 3];
      }
    }
  }
  red[q][lane] = acc;
  __syncthreads();
  if (q == 0) {
    float s = red[0][lane] + red[1][lane] + red[2][lane] + red[3][lane];
    out[(size_t)v*64 + lane] = s;
  }
}

// ---------------------------------------------------------------------------
// Downsample mask: mout[v] = OR over taps of in-bounds min_.
// ---------------------------------------------------------------------------
template<int ID,int IH,int IW,int OD,int OH,int OW,int KD,int KH,int KW,
         int SD,int SH,int SW,int PD,int PH,int PW>
__global__ __launch_bounds__(256)
void mask_down(const unsigned char* __restrict__ min_, unsigned char* __restrict__ mout) {
  int v = blockIdx.x * blockDim.x + threadIdx.x;
  if (v >= OD*OH*OW) return;
  int ox = v % OW; int t = v / OW; int oy = t % OH; int oz = t / OH;
  bool any = false;
  for (int kz = 0; kz < KD; kz++) {
    int iz = oz*SD - PD + kz; if ((unsigned)iz >= (unsigned)ID) continue;
    for (int ky = 0; ky < KH; ky++) {
      int iy = oy*SH - PH + ky; if ((unsigned)iy >= (unsigned)IH) continue;
      for (int kx = 0; kx < KW; kx++) {
        int ix = ox*SW - PW + kx; if ((unsigned)ix >= (unsigned)IW) continue;
        any = any || (min_[(iz*IH + iy)*IW + ix] != 0);
      }
    }
  }
  mout[v] = any ? 1 : 0;
}

// ---------------------------------------------------------------------------
// Masked BN stats: per-channel sum, sumsq, count.
// ---------------------------------------------------------------------------
template<int CO, int YD>
__global__ void bn_stats(const float* __restrict__ x, const unsigned char* __restrict__ m,
                         float* __restrict__ stats, int nvox) {
  int c  = threadIdx.x;
  int ty = threadIdx.y;
  float s = 0.f, q = 0.f, cnt = 0.f;
  for (int vox = blockIdx.x*YD + ty; vox < nvox; vox += gridDim.x*YD) {
    bool act = m ? (m[vox] != 0) : true;
    if (act) {
      float v = x[(size_t)vox*CO + c];
      s += v; q += v*v; cnt += 1.f;
    }
  }
  __shared__ float ls[YD][CO];
  __shared__ float lq[YD][CO];
  __shared__ float lc[YD];
  ls[ty][c] = s; lq[ty][c] = q;
  if (c == 0) lc[ty] = cnt;
  __syncthreads();
  if (ty == 0) {
    #pragma unroll
    for (int i = 1; i < YD; i++) { s += ls[i][c]; q += lq[i][c]; }
    atomicAdd(&stats[c], s);
    atomicAdd(&stats[CO + c], q);
    if (c == 0) {
      float tc = 0.f;
      #pragma unroll
      for (int i = 0; i < YD; i++) tc += lc[i];
      atomicAdd(&stats[2*CO], tc);
    }
  }
}

// ---------------------------------------------------------------------------
template<int CO>
__global__ __launch_bounds__(256)
void bn_apply(float* __restrict__ x, const unsigned char* __restrict__ m,
              const float* __restrict__ stats, const float* __restrict__ g,
              const float* __restrict__ b, int nvox) {
  int idx = blockIdx.x * blockDim.x + threadIdx.x;
  int vox = idx / CO, c = idx % CO;
  if (vox >= nvox) return;
  float cnt   = fmaxf(stats[2*CO], 1.f);
  float mean  = stats[c] / cnt;
  float var   = stats[CO + c] / cnt - mean*mean;
  float scale = g[c] * rsqrtf(var + EPSV);
  float v = (x[idx] - mean) * scale + b[c];
  v = fmaxf(v, 0.f);
  bool act = m ? (m[vox] != 0) : true;
  x[idx] = act ? v : 0.f;
}

// ---------------------------------------------------------------------------
// BN apply + dual output: fp32 in place AND bf16 copy (for MFMA consumer).
// ---------------------------------------------------------------------------
template<int CO>
__global__ __launch_bounds__(256)
void bn_apply_bf(float* __restrict__ x, const unsigned char* __restrict__ m,
                 const float* __restrict__ stats, const float* __restrict__ g,
                 const float* __restrict__ b, unsigned short* __restrict__ xb,
                 int nvox) {
  int idx = blockIdx.x * blockDim.x + threadIdx.x;
  int vox = idx / CO, c = idx % CO;
  if (vox >= nvox) return;
  float cnt   = fmaxf(stats[2*CO], 1.f);
  float mean  = stats[c] / cnt;
  float var   = stats[CO + c] / cnt - mean*mean;
  float scale = g[c] * rsqrtf(var + EPSV);
  float v = (x[idx] - mean) * scale + b[c];
  v = fmaxf(v, 0.f);
  bool act = m ? (m[vox] != 0) : true;
  v = act ? v : 0.f;
  x[idx]  = v;
  xb[idx] = f2bf(v);
}

// ---------------------------------------------------------------------------
__global__ __launch_bounds__(256)
void write_out(const float* __restrict__ x, float* __restrict__ out) {
  int idx = blockIdx.x * blockDim.x + threadIdx.x;
  if (idx >= 64*11*5*25) return;
  int y = idx % 25; int t = idx / 25;
  int z = t % 5;  t /= 5;
  int wx = t % 11; int c = t / 11;
  out[idx] = x[(((z*25 + y)*11) + wx)*64 + c];
}

// ---------------------------------------------------------------------------
extern "C" void kernel_launch(void* const* d_in, const int* in_sizes, int n_in,
                              void* d_out, int out_size, void* d_ws, size_t ws_size,
                              hipStream_t stream) {
  const float* vf    = (const float*)d_in[0];
  const int*   coors = (const int*)d_in[1];
  int n = in_sizes[0] / 16;

  // dict order is INTERLEAVED: vf, coors, bs, shape, (w0,g0,b0), (w1,g1,b1), ...
  const float *w[9], *g[9], *b[9];
  for (int i = 0; i < 9; i++) {
    w[i] = (const float*)d_in[4 + 3*i];
    g[i] = (const float*)d_in[5 + 3*i];
    b[i] = (const float*)d_in[6 + 3*i];
  }
  float* out = (float*)d_out;

  char* wsb = (char*)d_ws;
  size_t off = 0;
  auto alloc = [&](size_t bytes) -> void* {
    void* p = wsb + off;
    off += (bytes + 255) & ~(size_t)255;
    return p;
  };
  // NOTE alloc order: grid0, fA, fB FIRST and contiguous — the 12.8 MB xB
  // overlay (bf16 activations, 200000x32) reuses this region twice:
  //   (1) L2-out bf16 (read by convm3/L3), then (2) L3-out bf16 (read by
  //   convm/L4). Stream order guarantees no overlap of uses.
  int*   grid0 = (int*)  alloc((size_t)40*200*200*4);
  float* fA    = (float*)alloc((size_t)n*16*4);
  float* fB    = (float*)alloc((size_t)n*16*4);
  float* wp    = (float*)alloc((size_t)454656*4);
  float* wq    = (float*)alloc((size_t)233472*4);
  unsigned short* wq3 = (unsigned short*)alloc((size_t)27648*2);
  unsigned short* wq4 = (unsigned short*)alloc((size_t)55296*2);
  unsigned short* wq5 = (unsigned short*)alloc((size_t)110592*2);
  float* dA    = (float*)alloc((size_t)20*100*100*32*4);
  float* dB    = (float*)alloc((size_t)20*100*100*32*4);
  unsigned short* xB5 = (unsigned short*)alloc((size_t)25000*64*2);
  unsigned char* m2 = (unsigned char*)alloc(20*100*100);
  unsigned char* m4 = (unsigned char*)alloc(10*50*50);
  unsigned char* m6 = (unsigned char*)alloc(5*25*24);
  unsigned char* m8 = (unsigned char*)alloc(5*25*11);
  float* stats = (float*)alloc((size_t)9*160*4);
  unsigned short* xB = (unsigned short*)grid0;   // overlay (12.8 MB < 14.1 MB)

  float* st[9];
  for (int i = 0; i < 9; i++) st[i] = stats + i*160;

  hipMemsetAsync(grid0, 0xFF, (size_t)40*200*200*4, stream);
  hipMemsetAsync(stats, 0, (size_t)9*160*4, stream);

  WPtrs wps; for (int i = 0; i < 9; i++) wps.w[i] = w[i];
  repack_w<<<idiv(454656,256), 256, 0, stream>>>(wps, wp);
  repack_wq<<<idiv(233472,256), 256, 0, stream>>>(w[6], w[7], w[8], wq);
  repack_w3b<<<idiv(27648,256), 256, 0, stream>>>(w[3], wq3);
  repack_wmb<<<idiv(165888,256), 256, 0, stream>>>(w[4], w[5], wq4, wq5);
  scatter_grid<<<idiv(n,256), 256, 0, stream>>>(coors, grid0, n);

  const int WO0=0, WO1=6912, WO2=13824;
  const int WQ6=0, WQ7=110592, WQ8=221184;

  // ---- L0, L1: sparse subm 16->16 ----
  subm16<<<idiv(n,256), 256, 0, stream>>>(vf, fA, coors, grid0, wp + WO0, n);
  bn_stats<16,16><<<imin(256, idiv(n,16)), dim3(16,16), 0, stream>>>(fA, nullptr, st[0], n);
  bn_apply<16><<<idiv(n*16,256), 256, 0, stream>>>(fA, nullptr, st[0], g[0], b[0], n);

  subm16<<<idiv(n,256), 256, 0, stream>>>(fA, fB, coors, grid0, wp + WO1, n);
  bn_stats<16,16><<<imin(256, idiv(n,16)), dim3(16,16), 0, stream>>>(fB, nullptr, st[1], n);
  bn_apply<16><<<idiv(n*16,256), 256, 0, stream>>>(fB, nullptr, st[1], g[1], b[1], n);

  // ---- L2: down 16->32 -> dense (20,100,100); bn emits fp32 + bf16 ----
  down16to32<<<dim3(idiv(200000,256),2), 256, 0, stream>>>(fB, grid0, dA, m2, wp + WO2);
  bn_stats<32,8><<<imin(256, idiv(200000,8)), dim3(32,8), 0, stream>>>(dA, m2, st[2], 200000);
  bn_apply_bf<32><<<idiv(200000*32,256), 256, 0, stream>>>(dA, m2, st[2], g[2], b[2], xB, 200000);

  // ---- L3: subm 32->32 dense, bf16 MFMA; bn re-emits bf16 into xB ----
  convm3<<<200000/64, 256, 0, stream>>>(xB, dB, wq3);
  bn_stats<32,8><<<imin(256, idiv(200000,8)), dim3(32,8), 0, stream>>>(dB, m2, st[3], 200000);
  bn_apply_bf<32><<<idiv(200000*32,256), 256, 0, stream>>>(dB, m2, st[3], g[3], b[3], xB, 200000);

  // ---- L4: down 32->64 -> (10,50,50), bf16 MFMA + mask ----
  convm<20,100,100, 10,50,50, 32, 2,2,2, 1,1,1>
      <<<idiv(25000,64), 256, 0, stream>>>(xB, dA, wq4);
  mask_down<20,100,100, 10,50,50, 3,3,3, 2,2,2, 1,1,1>
      <<<idiv(25000,256), 256, 0, stream>>>(m2, m4);
  bn_stats<64,4><<<imin(256, idiv(25000,4)), dim3(64,4), 0, stream>>>(dA, m4, st[4], 25000);
  bn_apply_bf<64><<<idiv(25000*64,256), 256, 0, stream>>>(dA, m4, st[4], g[4], b[4], xB5, 25000);

  // ---- L5: subm 64->64, bf16 MFMA ----
  convm<10,50,50, 10,50,50, 64, 1,1,1, 1,1,1>
      <<<idiv(25000,64), 256, 0, stream>>>(xB5, dB, wq5);
  bn_stats<64,4><<<imin(256, idiv(25000,4)), dim3(64,4), 0, stream>>>(dB, m4, st[5], 25000);
  bn_apply<64><<<idiv(25000*64,256), 256, 0, stream>>>(dB, m4, st[5], g[5], b[5], 25000);

  // ---- L6: down 64->64 s(2,2,2) p(1,1,0) -> (5,25,24), block-per-voxel ----
  convt<10,50,50, 5,25,24, 3,3,3, 2,2,2, 1,1,0>
      <<<3000, 256, 0, stream>>>(dB, dA, wq + WQ6);
  mask_down<10,50,50, 5,25,24, 3,3,3, 2,2,2, 1,1,0>
      <<<idiv(3000,256), 256, 0, stream>>>(m4, m6);
  bn_stats<64,4><<<imin(256, idiv(3000,4)), dim3(64,4), 0, stream>>>(dA, m6, st[6], 3000);
  bn_apply<64><<<idiv(3000*64,256), 256, 0, stream>>>(dA, m6, st[6], g[6], b[6], 3000);

  // ---- L7: subm 64->64, block-per-voxel ----
  convt<5,25,24, 5,25,24, 3,3,3, 1,1,1, 1,1,1>
      <<<3000, 256, 0, stream>>>(dA, dB, wq + WQ7);
  bn_stats<64,4><<<imin(256, idiv(3000,4)), dim3(64,4), 0, stream>>>(dB, m6, st[7], 3000);
  bn_apply<64><<<idiv(3000*64,256), 256, 0, stream>>>(dB, m6, st[7], g[7], b[7], 3000);

  // ---- L8: down 64->64 k(1,1,3) s(1,1,2) -> (5,25,11), block-per-voxel ----
  convt<5,25,24, 5,25,11, 1,1,3, 1,1,2, 0,0,0>
      <<<1375, 256, 0, stream>>>(dB, dA, wq + WQ8);
  mask_down<5,25,24, 5,25,11, 1,1,3, 1,1,2, 0,0,0>
      <<<idiv(1375,256), 256, 0, stream>>>(m6, m8);
  bn_stats<64,4><<<imin(256, idiv(1375,4)), dim3(64,4), 0, stream>>>(dA, m8, st[8], 1375);
  bn_apply<64><<<idiv(1375*64,256), 256, 0, stream>>>(dA, m8, st[8], g[8], b[8], 1375);

  write_out<<<idiv(88000,256), 256, 0, stream>>>(dA, out);
}